// Round 5
// baseline (969.069 us; speedup 1.0000x reference)
//
#include <hip/hip_runtime.h>
#include <math.h>

#define B_ 2
#define N_ 4096
#define D_ 768
#define H_ 12
#define DH_ 64
#define NB_ 64
#define FF_ 3072
#define LAYERS_ 2
#define ROWS_ (B_ * N_)   // 8192

typedef __attribute__((ext_vector_type(8))) short s16x8;            // bf16x8 frag
typedef __attribute__((ext_vector_type(8))) unsigned short u16x8;   // staging
typedef __attribute__((ext_vector_type(4))) float f32x4;

typedef const __attribute__((address_space(1))) unsigned int ga_u32;
typedef __attribute__((address_space(3))) unsigned int lds_u32;

static __device__ __forceinline__ float gelu_fast(float x) {
    // 0.5x(1+tanh(z)) == x*sigmoid(2z), z = sqrt(2/pi)(x+0.044715x^3)
    float z2 = 1.5957691216057308f * x * (1.0f + 0.044715f * x * x);
    return x * __builtin_amdgcn_rcpf(1.0f + __expf(-z2));
}

static __device__ __forceinline__ unsigned bf16_rne(float f) {
    unsigned u = __float_as_uint(f);
    return (u + 0x7FFFu + ((u >> 16) & 1u)) >> 16;
}
static __device__ __forceinline__ float bfh2f(unsigned short h) {
    return __uint_as_float(((unsigned)h) << 16);
}

// ---------------------------------------------------------------------------
// Weight prep: T[n][k] = bf16(W[k][n]); LDS tiled 64x64.
// ---------------------------------------------------------------------------
__global__ __launch_bounds__(256)
void transpose_bf16(const float* __restrict__ W, unsigned short* __restrict__ T,
                    int K, int N) {
    __shared__ unsigned short tile[64][72];
    const int k0 = blockIdx.y * 64, n0 = blockIdx.x * 64;
    const int t = threadIdx.x;
    const int r = t >> 2, c0 = (t & 3) * 16;
    const float* src = W + (size_t)(k0 + r) * N + n0 + c0;
#pragma unroll
    for (int j = 0; j < 4; ++j) {
        float4 v = *(const float4*)(src + j * 4);
        tile[r][c0 + j * 4 + 0] = (unsigned short)bf16_rne(v.x);
        tile[r][c0 + j * 4 + 1] = (unsigned short)bf16_rne(v.y);
        tile[r][c0 + j * 4 + 2] = (unsigned short)bf16_rne(v.z);
        tile[r][c0 + j * 4 + 3] = (unsigned short)bf16_rne(v.w);
    }
    __syncthreads();
    const int nr = t >> 2, kc = (t & 3) * 16;
    unsigned short* dst = T + (size_t)(n0 + nr) * K + k0 + kc;
    ushort4 o;
#pragma unroll
    for (int j = 0; j < 4; ++j) {
        o.x = tile[kc + j * 4 + 0][nr];
        o.y = tile[kc + j * 4 + 1][nr];
        o.z = tile[kc + j * 4 + 2][nr];
        o.w = tile[kc + j * 4 + 3][nr];
        *(ushort4*)(dst + j * 4) = o;
    }
}

// ---------------------------------------------------------------------------
// bf16 GEMM core, BK=64: C[M,N] = A[M,K] @ Bt[N,K]^T + bias.
// 128x128 tile, 256 thr; 8 global_load_lds + 32 MFMA per barrier pair.
// OMODE: 0 = fp32 direct stores, 1 = bf16 via LDS-roundtrip coalesced stores.
// ---------------------------------------------------------------------------
template <int OMODE>
__global__ __launch_bounds__(256)
void gemm_bt(const unsigned short* __restrict__ A, const unsigned short* __restrict__ Bt,
             const float* __restrict__ bias, void* __restrict__ Cv,
             int M, int N, int K, int gelu) {
    __shared__ __align__(16) unsigned short smem[2 * 128 * 64];   // 32 KB
    unsigned short* sA = smem;
    unsigned short* sB = smem + 128 * 64;
    const int tid = threadIdx.x, lane = tid & 63, wid = tid >> 6;
    const int row0 = blockIdx.y * 128, col0 = blockIdx.x * 128;
    const int rh = (wid >> 1) * 64, ch = (wid & 1) * 64;
    const int fr = lane & 15, fq = lane >> 4;
    const int sr = lane >> 3;           // 0..7 row in 8-row group
    const int sk = (lane & 7) * 8;      // k offset (u16)

    f32x4 acc[4][4] = {};
    for (int k0 = 0; k0 < K; k0 += 64) {
        __syncthreads();   // previous tile's reads done
#pragma unroll
        for (int c = 0; c < 4; ++c) {
            int rbase = wid * 8 + c * 32;
            __builtin_amdgcn_global_load_lds(
                (ga_u32*)(A + (size_t)(row0 + rbase + sr) * K + k0 + sk),
                (lds_u32*)&sA[rbase * 64], 16, 0, 0);
            __builtin_amdgcn_global_load_lds(
                (ga_u32*)(Bt + (size_t)(col0 + rbase + sr) * K + k0 + sk),
                (lds_u32*)&sB[rbase * 64], 16, 0, 0);
        }
        __syncthreads();   // vmcnt drained -> tile visible
#pragma unroll
        for (int half = 0; half < 2; ++half) {
            s16x8 af[4], bf[4];
#pragma unroll
            for (int i = 0; i < 4; ++i)
                af[i] = *(const s16x8*)&sA[(rh + 16 * i + fr) * 64 + half * 32 + fq * 8];
#pragma unroll
            for (int j = 0; j < 4; ++j)
                bf[j] = *(const s16x8*)&sB[(ch + 16 * j + fr) * 64 + half * 32 + fq * 8];
#pragma unroll
            for (int i = 0; i < 4; ++i)
#pragma unroll
                for (int j = 0; j < 4; ++j)
                    acc[i][j] = __builtin_amdgcn_mfma_f32_16x16x32_bf16(af[i], bf[j], acc[i][j], 0, 0, 0);
        }
    }
    if (OMODE == 0) {
#pragma unroll
        for (int j = 0; j < 4; ++j) {
            int col = col0 + ch + 16 * j + fr;
            float bb = bias[col];
#pragma unroll
            for (int i = 0; i < 4; ++i)
#pragma unroll
                for (int r = 0; r < 4; ++r) {
                    int row = row0 + rh + 16 * i + fq * 4 + r;
                    float v = acc[i][j][r] + bb;
                    if (gelu) v = gelu_fast(v);
                    ((float*)Cv)[(size_t)row * N + col] = v;
                }
        }
    } else {
        // LDS roundtrip: 64 rows per phase, padded stride 132 (conflict-free)
        unsigned short* sC = smem;
#pragma unroll
        for (int hh = 0; hh < 2; ++hh) {
            __syncthreads();
            if ((wid >> 1) == hh) {
#pragma unroll
                for (int j = 0; j < 4; ++j) {
                    float bb = bias[col0 + ch + 16 * j + fr];
#pragma unroll
                    for (int i = 0; i < 4; ++i)
#pragma unroll
                        for (int r = 0; r < 4; ++r) {
                            float v = acc[i][j][r] + bb;
                            if (gelu) v = gelu_fast(v);
                            sC[(16 * i + fq * 4 + r) * 132 + ch + 16 * j + fr] =
                                (unsigned short)bf16_rne(v);
                        }
                }
            }
            __syncthreads();
#pragma unroll
            for (int p = 0; p < 4; ++p) {
                int seg = p * 256 + tid;
                int r = seg >> 4, c8 = (seg & 15) * 8;
                *(u16x8*)&((unsigned short*)Cv)[(size_t)(row0 + hh * 64 + r) * N + col0 + c8] =
                    *(const u16x8*)&sC[r * 132 + c8];
            }
        }
    }
}

// Fused QKV GEMM (BK=64): N=2304 packed [Wq^T;Wk^T;Wv^T].
// seg 0 -> Qh, 1 -> Kh (both via LDS-roundtrip bf16), 2 -> VT transposed b64.
__global__ __launch_bounds__(256)
void gemm_qkv(const unsigned short* __restrict__ A, const unsigned short* __restrict__ Bt,
              const float* __restrict__ bq, const float* __restrict__ bk,
              const float* __restrict__ bv,
              unsigned short* __restrict__ Qh, unsigned short* __restrict__ Kh,
              unsigned short* __restrict__ VT) {
    const int K = D_;
    __shared__ __align__(16) unsigned short smem[2 * 128 * 64];
    unsigned short* sA = smem;
    unsigned short* sB = smem + 128 * 64;
    const int tid = threadIdx.x, lane = tid & 63, wid = tid >> 6;
    const int row0 = blockIdx.y * 128, col0 = blockIdx.x * 128;
    const int rh = (wid >> 1) * 64, ch = (wid & 1) * 64;
    const int fr = lane & 15, fq = lane >> 4;
    const int sr = lane >> 3, sk = (lane & 7) * 8;

    f32x4 acc[4][4] = {};
    for (int k0 = 0; k0 < K; k0 += 64) {
        __syncthreads();
#pragma unroll
        for (int c = 0; c < 4; ++c) {
            int rbase = wid * 8 + c * 32;
            __builtin_amdgcn_global_load_lds(
                (ga_u32*)(A + (size_t)(row0 + rbase + sr) * K + k0 + sk),
                (lds_u32*)&sA[rbase * 64], 16, 0, 0);
            __builtin_amdgcn_global_load_lds(
                (ga_u32*)(Bt + (size_t)(col0 + rbase + sr) * K + k0 + sk),
                (lds_u32*)&sB[rbase * 64], 16, 0, 0);
        }
        __syncthreads();
#pragma unroll
        for (int half = 0; half < 2; ++half) {
            s16x8 af[4], bf[4];
#pragma unroll
            for (int i = 0; i < 4; ++i)
                af[i] = *(const s16x8*)&sA[(rh + 16 * i + fr) * 64 + half * 32 + fq * 8];
#pragma unroll
            for (int j = 0; j < 4; ++j)
                bf[j] = *(const s16x8*)&sB[(ch + 16 * j + fr) * 64 + half * 32 + fq * 8];
#pragma unroll
            for (int i = 0; i < 4; ++i)
#pragma unroll
                for (int j = 0; j < 4; ++j)
                    acc[i][j] = __builtin_amdgcn_mfma_f32_16x16x32_bf16(af[i], bf[j], acc[i][j], 0, 0, 0);
        }
    }
    const int seg = blockIdx.x / 6;
    const int colbase = col0 - seg * D_;   // 0..640 within segment
    const float* bias = (seg == 0) ? bq : (seg == 1) ? bk : bv;
    if (seg == 2) {
#pragma unroll
        for (int j = 0; j < 4; ++j) {
            int col_l = colbase + ch + 16 * j + fr;
            float bb = bias[col_l];
#pragma unroll
            for (int i = 0; i < 4; ++i) {
                int rowbase = row0 + rh + 16 * i + fq * 4;
                ushort4 o;
                o.x = (unsigned short)bf16_rne(acc[i][j][0] + bb);
                o.y = (unsigned short)bf16_rne(acc[i][j][1] + bb);
                o.z = (unsigned short)bf16_rne(acc[i][j][2] + bb);
                o.w = (unsigned short)bf16_rne(acc[i][j][3] + bb);
                *(ushort4*)&VT[(size_t)col_l * ROWS_ + rowbase] = o;
            }
        }
    } else {
        unsigned short* dst = (seg == 0) ? Qh : Kh;
        unsigned short* sC = smem;
#pragma unroll
        for (int hh = 0; hh < 2; ++hh) {
            __syncthreads();
            if ((wid >> 1) == hh) {
#pragma unroll
                for (int j = 0; j < 4; ++j) {
                    float bb = bias[colbase + ch + 16 * j + fr];
#pragma unroll
                    for (int i = 0; i < 4; ++i)
#pragma unroll
                        for (int r = 0; r < 4; ++r)
                            sC[(16 * i + fq * 4 + r) * 132 + ch + 16 * j + fr] =
                                (unsigned short)bf16_rne(acc[i][j][r] + bb);
                }
            }
            __syncthreads();
#pragma unroll
            for (int p = 0; p < 4; ++p) {
                int seg2 = p * 256 + tid;
                int r = seg2 >> 4, c8 = (seg2 & 15) * 8;
                *(u16x8*)&dst[(size_t)(row0 + hh * 64 + r) * D_ + colbase + c8] =
                    *(const u16x8*)&sC[r * 132 + c8];
            }
        }
    }
}

// ---------------------------------------------------------------------------
// bf16 MFMA block-sparse attention (verified round 3, unchanged).
// ---------------------------------------------------------------------------
template <bool EDGE>
__global__ __launch_bounds__(256, 4)
void attn_mfma(const unsigned short* __restrict__ Qb, const unsigned short* __restrict__ Kb,
               const unsigned short* __restrict__ VTb, const int* __restrict__ rb,
               unsigned short* __restrict__ ctx, float* __restrict__ scratch) {
    __shared__ __align__(16) unsigned short sQ[64][72];
    __shared__ __align__(16) unsigned short sK[64][72];
    __shared__ __align__(16) unsigned short sVT[64][72];
    __shared__ __align__(16) unsigned short sP[4][16][72];
    __shared__ int sList[16];
    const int tid = threadIdx.x, lane = tid & 63, wid = tid >> 6;
    const int fr = lane & 15, fq = lane >> 4;
    int qb, h, b, nkb, slice = 0;
    if (EDGE) {
        int part = blockIdx.x & 3;
        int hh = (blockIdx.x >> 2) % H_;
        int be = (blockIdx.x >> 2) / H_;
        int eb = be & 1;
        b = be >> 1;
        h = hh;
        qb = eb ? (NB_ - 1) : 0;
        nkb = 16;
        slice = ((b * 2 + eb) * H_ + h) * 4 + part;
        if (tid < 16) sList[tid] = part * 16 + tid;
    } else {
        qb = blockIdx.x % (NB_ - 2) + 1;
        h = (blockIdx.x / (NB_ - 2)) % H_;
        b = blockIdx.x / ((NB_ - 2) * H_);
        nkb = 8;
        if (tid < 8) {
            int e;
            if (tid == 0) e = 0;
            else if (tid == 1) e = NB_ - 1;
            else if (tid < 5) e = qb + (tid - 3);
            else e = rb[(h * NB_ + qb) * 3 + (tid - 5)];
            sList[tid] = e;
        }
    }
    const int qrow0 = b * N_ + qb * 64;
    const unsigned short* Qg = Qb + (size_t)qrow0 * D_ + h * 64;
#pragma unroll
    for (int p = 0; p < 2; ++p) {
        int idx = p * 256 + tid;
        int r = idx >> 3, o = (idx & 7) * 8;
        *(u16x8*)&sQ[r][o] = *(const u16x8*)(Qg + (size_t)r * D_ + o);
    }
    f32x4 oacc[4] = {};
    float l_part[4] = {};
    __syncthreads();
    s16x8 aq0 = *(const s16x8*)&sQ[wid * 16 + fr][fq * 8];
    s16x8 aq1 = *(const s16x8*)&sQ[wid * 16 + fr][32 + fq * 8];

    for (int kb = 0; kb < nkb; ++kb) {
        const int kblk = sList[kb];
        const int keyrow0 = b * N_ + kblk * 64;
        __syncthreads();
        const unsigned short* Kg = Kb + (size_t)keyrow0 * D_ + h * 64;
#pragma unroll
        for (int p = 0; p < 2; ++p) {
            int idx = p * 256 + tid;
            int r = idx >> 3, o = (idx & 7) * 8;
            *(u16x8*)&sK[r][o] = *(const u16x8*)(Kg + (size_t)r * D_ + o);
        }
        const unsigned short* Vg = VTb + (size_t)(h * 64) * ROWS_ + keyrow0;
#pragma unroll
        for (int p = 0; p < 2; ++p) {
            int idx = p * 256 + tid;
            int d = idx >> 3, o = (idx & 7) * 8;
            *(u16x8*)&sVT[d][o] = *(const u16x8*)(Vg + (size_t)d * ROWS_ + o);
        }
        __syncthreads();
#pragma unroll
        for (int g = 0; g < 4; ++g) {
            s16x8 bk0 = *(const s16x8*)&sK[g * 16 + fr][fq * 8];
            s16x8 bk1 = *(const s16x8*)&sK[g * 16 + fr][32 + fq * 8];
            f32x4 s = {};
            s = __builtin_amdgcn_mfma_f32_16x16x32_bf16(aq0, bk0, s, 0, 0, 0);
            s = __builtin_amdgcn_mfma_f32_16x16x32_bf16(aq1, bk1, s, 0, 0, 0);
#pragma unroll
            for (int r = 0; r < 4; ++r) {
                float pv = __expf(s[r] * 0.125f);
                l_part[r] += pv;
                sP[wid][fq * 4 + r][g * 16 + fr] = (unsigned short)bf16_rne(pv);
            }
        }
        s16x8 ap0 = *(const s16x8*)&sP[wid][fr][fq * 8];
        s16x8 ap1 = *(const s16x8*)&sP[wid][fr][32 + fq * 8];
#pragma unroll
        for (int g = 0; g < 4; ++g) {
            s16x8 bv0 = *(const s16x8*)&sVT[g * 16 + fr][fq * 8];
            s16x8 bv1 = *(const s16x8*)&sVT[g * 16 + fr][32 + fq * 8];
            oacc[g] = __builtin_amdgcn_mfma_f32_16x16x32_bf16(ap0, bv0, oacc[g], 0, 0, 0);
            oacc[g] = __builtin_amdgcn_mfma_f32_16x16x32_bf16(ap1, bv1, oacc[g], 0, 0, 0);
        }
    }
    float l4[4];
#pragma unroll
    for (int r = 0; r < 4; ++r) {
        float lv = l_part[r];
        lv += __shfl_xor(lv, 1, 64);
        lv += __shfl_xor(lv, 2, 64);
        lv += __shfl_xor(lv, 4, 64);
        lv += __shfl_xor(lv, 8, 64);
        l4[r] = lv;
    }
    if (EDGE) {
        float* sc = scratch + (size_t)slice * (64 * 64 + 64);
#pragma unroll
        for (int g = 0; g < 4; ++g)
#pragma unroll
            for (int r = 0; r < 4; ++r)
                sc[(wid * 16 + fq * 4 + r) * 64 + g * 16 + fr] = oacc[g][r];
        if (fr == 0) {
#pragma unroll
            for (int r = 0; r < 4; ++r)
                sc[4096 + wid * 16 + fq * 4 + r] = l4[r];
        }
    } else {
        __syncthreads();
#pragma unroll
        for (int g = 0; g < 4; ++g) {
#pragma unroll
            for (int r = 0; r < 4; ++r) {
                float v = oacc[g][r] / l4[r];
                sK[wid * 16 + fq * 4 + r][g * 16 + fr] = (unsigned short)bf16_rne(v);
            }
        }
        __syncthreads();
        unsigned short* Cg = ctx + (size_t)qrow0 * D_ + h * 64;
#pragma unroll
        for (int p = 0; p < 2; ++p) {
            int idx = p * 256 + tid;
            int r = idx >> 3, o = (idx & 7) * 8;
            *(u16x8*)(Cg + (size_t)r * D_ + o) = *(const u16x8*)&sK[r][o];
        }
    }
}

__global__ __launch_bounds__(256)
void edge_combine(const float* __restrict__ scratch, unsigned short* __restrict__ ctx) {
    const int bid = blockIdx.x;
    const int h = bid % H_;
    const int eb = (bid / H_) & 1;
    const int b = bid / (2 * H_);
    const int qb = eb ? (NB_ - 1) : 0;
    const int qrow0 = b * N_ + qb * 64;
    const int slice0 = bid * 4;
    for (int e = threadIdx.x; e < 4096; e += 256) {
        int row = e >> 6, col = e & 63;
        float o = 0.f, l = 0.f;
#pragma unroll
        for (int p = 0; p < 4; ++p) {
            const float* sc = scratch + (size_t)(slice0 + p) * (64 * 64 + 64);
            o += sc[row * 64 + col];
            l += sc[4096 + row];
        }
        ctx[(size_t)(qrow0 + row) * D_ + h * 64 + col] = (unsigned short)bf16_rne(o / l);
    }
}

// ---------------------------------------------------------------------------
// LayerNorm — bf16 residual stream, fp32 math.
// ---------------------------------------------------------------------------
__global__ __launch_bounds__(256)
void embed_ln_kernel(const float* __restrict__ emb, const float* __restrict__ pos,
                     const float* __restrict__ tt, const float* __restrict__ g,
                     const float* __restrict__ bb, unsigned short* __restrict__ out) {
    __shared__ float red1[4], red2[4];
    const int row = blockIdx.x;
    const int n = row & (N_ - 1);
    const int t = threadIdx.x;
    float v[3];
#pragma unroll
    for (int i = 0; i < 3; ++i) {
        int d = t + i * 256;
        v[i] = emb[(size_t)row * D_ + d] + pos[(size_t)n * D_ + d] + tt[d];
    }
    float s = v[0] + v[1] + v[2];
#pragma unroll
    for (int off = 32; off > 0; off >>= 1) s += __shfl_xor(s, off, 64);
    if ((t & 63) == 0) red1[t >> 6] = s;
    __syncthreads();
    float mu = (red1[0] + red1[1] + red1[2] + red1[3]) * (1.0f / D_);
    float q = 0;
#pragma unroll
    for (int i = 0; i < 3; ++i) { float dv = v[i] - mu; q += dv * dv; }
#pragma unroll
    for (int off = 32; off > 0; off >>= 1) q += __shfl_xor(q, off, 64);
    if ((t & 63) == 0) red2[t >> 6] = q;
    __syncthreads();
    float var = (red2[0] + red2[1] + red2[2] + red2[3]) * (1.0f / D_);
    float rs = rsqrtf(var + 1e-12f);
#pragma unroll
    for (int i = 0; i < 3; ++i) {
        int d = t + i * 256;
        out[(size_t)row * D_ + d] = (unsigned short)bf16_rne((v[i] - mu) * rs * g[d] + bb[d]);
    }
}

__global__ __launch_bounds__(256)
void add_ln_kernel(const unsigned short* __restrict__ X, const float* __restrict__ Y,
                   const float* __restrict__ g, const float* __restrict__ bb,
                   unsigned short* __restrict__ out) {
    __shared__ float red1[4], red2[4];
    const int row = blockIdx.x;
    const int t = threadIdx.x;
    float v[3];
#pragma unroll
    for (int i = 0; i < 3; ++i) {
        int d = t + i * 256;
        v[i] = bfh2f(X[(size_t)row * D_ + d]) + Y[(size_t)row * D_ + d];
    }
    float s = v[0] + v[1] + v[2];
#pragma unroll
    for (int off = 32; off > 0; off >>= 1) s += __shfl_xor(s, off, 64);
    if ((t & 63) == 0) red1[t >> 6] = s;
    __syncthreads();
    float mu = (red1[0] + red1[1] + red1[2] + red1[3]) * (1.0f / D_);
    float q = 0;
#pragma unroll
    for (int i = 0; i < 3; ++i) { float dv = v[i] - mu; q += dv * dv; }
#pragma unroll
    for (int off = 32; off > 0; off >>= 1) q += __shfl_xor(q, off, 64);
    if ((t & 63) == 0) red2[t >> 6] = q;
    __syncthreads();
    float var = (red2[0] + red2[1] + red2[2] + red2[3]) * (1.0f / D_);
    float rs = rsqrtf(var + 1e-12f);
#pragma unroll
    for (int i = 0; i < 3; ++i) {
        int d = t + i * 256;
        out[(size_t)row * D_ + d] = (unsigned short)bf16_rne((v[i] - mu) * rs * g[d] + bb[d]);
    }
}

// ---------------------------------------------------------------------------
// Mean-pool over N then fc
// ---------------------------------------------------------------------------
__global__ __launch_bounds__(256)
void pool_partial_kernel(const unsigned short* __restrict__ X, float* __restrict__ partial) {
    int blk = blockIdx.x;
    int b = blk >> 4, c = blk & 15;
    int t = threadIdx.x;
#pragma unroll
    for (int i = 0; i < 3; ++i) {
        int d = t + i * 256;
        float s = 0.f;
        for (int n = 0; n < 256; ++n)
            s += bfh2f(X[((size_t)(b * N_ + c * 256 + n)) * D_ + d]);
        partial[(size_t)(b * 16 + c) * D_ + d] = s;
    }
}

__global__ __launch_bounds__(256)
void pool_final_kernel(const float* __restrict__ partial, const float* __restrict__ fcw,
                       const float* __restrict__ fcb, float* __restrict__ out) {
    __shared__ float red[4];
    int t = threadIdx.x;
    for (int b = 0; b < B_; ++b) {
        float s = 0.f;
#pragma unroll
        for (int i = 0; i < 3; ++i) {
            int d = t + i * 256;
            float ps = 0.f;
#pragma unroll
            for (int c = 0; c < 16; ++c) ps += partial[(size_t)(b * 16 + c) * D_ + d];
            s += ps * (1.0f / N_) * fcw[d];
        }
#pragma unroll
        for (int off = 32; off > 0; off >>= 1) s += __shfl_xor(s, off, 64);
        __syncthreads();
        if ((t & 63) == 0) red[t >> 6] = s;
        __syncthreads();
        if (t == 0) out[b] = red[0] + red[1] + red[2] + red[3] + fcb[0];
    }
}

// ---------------------------------------------------------------------------
extern "C" void kernel_launch(void* const* d_in, const int* in_sizes, int n_in,
                              void* d_out, int out_size, void* d_ws, size_t ws_size,
                              hipStream_t stream) {
    (void)in_sizes; (void)n_in; (void)out_size; (void)ws_size;
    const float* emb  = (const float*)d_in[0];
    const int*   rblk = (const int*)d_in[1];
    const float* pos  = (const float*)d_in[2];
    const float* tt   = (const float*)d_in[3];
    const float* elg  = (const float*)d_in[4];
    const float* elb  = (const float*)d_in[5];
    const float* Wq   = (const float*)d_in[6];
    const float* bq   = (const float*)d_in[7];
    const float* Wk   = (const float*)d_in[8];
    const float* bk   = (const float*)d_in[9];
    const float* Wv   = (const float*)d_in[10];
    const float* bv   = (const float*)d_in[11];
    const float* Wo   = (const float*)d_in[12];
    const float* bo   = (const float*)d_in[13];
    const float* ln1g = (const float*)d_in[14];
    const float* ln1b = (const float*)d_in[15];
    const float* Wi   = (const float*)d_in[16];
    const float* bi   = (const float*)d_in[17];
    const float* Wd   = (const float*)d_in[18];
    const float* bd   = (const float*)d_in[19];
    const float* ln2g = (const float*)d_in[20];
    const float* ln2b = (const float*)d_in[21];
    const float* fcw  = (const float*)d_in[22];
    const float* fcb  = (const float*)d_in[23];
    float* outp = (float*)d_out;

    const size_t R = (size_t)ROWS_ * D_;          // 6,291,456
    float* base = (float*)d_ws;
    unsigned short* Xh  = (unsigned short*)base;
    unsigned short* Abh = (unsigned short*)(base + R / 2);
    float* G32 = base + R;
    unsigned short* Qh  = (unsigned short*)(base + 2 * R);
    unsigned short* Kh  = (unsigned short*)(base + 2 * R + R / 2);
    unsigned short* VTh = (unsigned short*)(base + 3 * R);
    unsigned short* Ch  = (unsigned short*)(base + 3 * R + R / 2);
    unsigned short* Hh  = (unsigned short*)(base + 2 * R);    // FFN hidden overlays QKVC
    unsigned short* Wt  = (unsigned short*)(base + 4 * R);
    float* Esc = base + 4 * R + 7077888;
    float* Pp  = Esc + 798720;

    const size_t LW = 7077888;
    const int rows = ROWS_;
    dim3 blk(256);

    for (int l = 0; l < LAYERS_; ++l) {
        unsigned short* QKVt = Wt + l * LW;
        unsigned short* Ot = QKVt + 2304 * 768;
        unsigned short* It = Ot + 768 * 768;
        unsigned short* Dt = It + 3072 * 768;
        transpose_bf16<<<dim3(12, 12), blk, 0, stream>>>(Wq + (size_t)l * D_ * D_, QKVt, 768, 768);
        transpose_bf16<<<dim3(12, 12), blk, 0, stream>>>(Wk + (size_t)l * D_ * D_, QKVt + 768 * 768, 768, 768);
        transpose_bf16<<<dim3(12, 12), blk, 0, stream>>>(Wv + (size_t)l * D_ * D_, QKVt + 1536 * 768, 768, 768);
        transpose_bf16<<<dim3(12, 12), blk, 0, stream>>>(Wo + (size_t)l * D_ * D_, Ot, 768, 768);
        transpose_bf16<<<dim3(48, 12), blk, 0, stream>>>(Wi + (size_t)l * D_ * FF_, It, 768, 3072);
        transpose_bf16<<<dim3(12, 48), blk, 0, stream>>>(Wd + (size_t)l * FF_ * D_, Dt, 3072, 768);
    }

    embed_ln_kernel<<<rows, blk, 0, stream>>>(emb, pos, tt, elg, elb, Xh);

    for (int l = 0; l < LAYERS_; ++l) {
        const float* bq_l = bq + (size_t)l * D_;
        const float* bk_l = bk + (size_t)l * D_;
        const float* bv_l = bv + (size_t)l * D_;
        const float* bo_l = bo + (size_t)l * D_;
        const float* bi_l = bi + (size_t)l * FF_;
        const float* bd_l = bd + (size_t)l * D_;
        const float* l1g = ln1g + (size_t)l * D_;
        const float* l1b = ln1b + (size_t)l * D_;
        const float* l2g = ln2g + (size_t)l * D_;
        const float* l2b = ln2b + (size_t)l * D_;
        const int* rb_l = rblk + (size_t)l * H_ * NB_ * 3;
        unsigned short* QKVt = Wt + l * LW;
        unsigned short* Ot = QKVt + 2304 * 768;
        unsigned short* It = Ot + 768 * 768;
        unsigned short* Dt = It + 3072 * 768;

        gemm_qkv<<<dim3(18, 64), blk, 0, stream>>>(Xh, QKVt, bq_l, bk_l, bv_l, Qh, Kh, VTh);

        attn_mfma<false><<<B_ * H_ * (NB_ - 2), blk, 0, stream>>>(Qh, Kh, VTh, rb_l, Ch, Esc);
        attn_mfma<true><<<B_ * 2 * H_ * 4, blk, 0, stream>>>(Qh, Kh, VTh, rb_l, Ch, Esc);
        edge_combine<<<B_ * 2 * H_, blk, 0, stream>>>(Esc, Ch);

        gemm_bt<0><<<dim3(6, 64), blk, 0, stream>>>(Ch, Ot, bo_l, G32, rows, D_, D_, 0);
        add_ln_kernel<<<rows, blk, 0, stream>>>(Xh, G32, l1g, l1b, Abh);

        gemm_bt<1><<<dim3(24, 64), blk, 0, stream>>>(Abh, It, bi_l, Hh, rows, FF_, D_, 1);
        gemm_bt<0><<<dim3(6, 64), blk, 0, stream>>>(Hh, Dt, bd_l, G32, rows, D_, FF_, 0);

        add_ln_kernel<<<rows, blk, 0, stream>>>(Abh, G32, l2g, l2b, Xh);
    }

    pool_partial_kernel<<<B_ * 16, blk, 0, stream>>>(Xh, Pp);
    pool_final_kernel<<<1, blk, 0, stream>>>(Pp, fcw, fcb, outp);
}

// Round 6
// 830.760 us; speedup vs baseline: 1.1665x; 1.1665x over previous
//
#include <hip/hip_runtime.h>
#include <math.h>

#define B_ 2
#define N_ 4096
#define D_ 768
#define H_ 12
#define DH_ 64
#define NB_ 64
#define FF_ 3072
#define LAYERS_ 2
#define ROWS_ (B_ * N_)   // 8192

typedef __attribute__((ext_vector_type(8))) short s16x8;            // bf16x8 frag
typedef __attribute__((ext_vector_type(8))) unsigned short u16x8;   // staging
typedef __attribute__((ext_vector_type(4))) float f32x4;

typedef const __attribute__((address_space(1))) unsigned int ga_u32;
typedef __attribute__((address_space(3))) unsigned int lds_u32;

static __device__ __forceinline__ float gelu_fast(float x) {
    // 0.5x(1+tanh(z)) == x*sigmoid(2z), z = sqrt(2/pi)(x+0.044715x^3)
    float z2 = 1.5957691216057308f * x * (1.0f + 0.044715f * x * x);
    return x * __builtin_amdgcn_rcpf(1.0f + __expf(-z2));
}

static __device__ __forceinline__ unsigned bf16_rne(float f) {
    unsigned u = __float_as_uint(f);
    return (u + 0x7FFFu + ((u >> 16) & 1u)) >> 16;
}
static __device__ __forceinline__ float bfh2f(unsigned short h) {
    return __uint_as_float(((unsigned)h) << 16);
}

// ---------------------------------------------------------------------------
// Weight prep, all transposes in ONE launch. Each block: one 64x64 tile.
// Layout per layer in Wt: [Q^T 768x768][K^T][V^T][O^T][I^T 3072x768][D^T 768x3072]
// ---------------------------------------------------------------------------
__global__ __launch_bounds__(256)
void prep_weights(const float* __restrict__ Wq, const float* __restrict__ Wk,
                  const float* __restrict__ Wv, const float* __restrict__ Wo,
                  const float* __restrict__ Wi, const float* __restrict__ Wd,
                  unsigned short* __restrict__ Wt) {
    const size_t LW = 7077888;
    int bid = blockIdx.x;
    int l = bid / 1728, r = bid % 1728;
    const float* W; unsigned short* T; int K, N, t, nx;
    if (r < 576) {
        int which = r / 144; t = r % 144; nx = 12; K = 768; N = 768;
        W = (which == 0 ? Wq : which == 1 ? Wk : which == 2 ? Wv : Wo) + (size_t)l * D_ * D_;
        T = Wt + l * LW + (size_t)(which < 3 ? which * 768 * 768 : 2304 * 768);
    } else if (r < 1152) {
        t = r - 576; nx = 48; K = 768; N = 3072;
        W = Wi + (size_t)l * D_ * FF_;
        T = Wt + l * LW + (size_t)(2304 * 768 + 768 * 768);
    } else {
        t = r - 1152; nx = 12; K = 3072; N = 768;
        W = Wd + (size_t)l * FF_ * D_;
        T = Wt + l * LW + (size_t)(2304 * 768 + 768 * 768 + 3072 * 768);
    }
    const int bx = t % nx, by = t / nx;
    __shared__ unsigned short tile[64][72];
    const int k0 = by * 64, n0 = bx * 64;
    const int tt = threadIdx.x;
    const int rr = tt >> 2, c0 = (tt & 3) * 16;
    const float* src = W + (size_t)(k0 + rr) * N + n0 + c0;
#pragma unroll
    for (int j = 0; j < 4; ++j) {
        float4 v = *(const float4*)(src + j * 4);
        tile[rr][c0 + j * 4 + 0] = (unsigned short)bf16_rne(v.x);
        tile[rr][c0 + j * 4 + 1] = (unsigned short)bf16_rne(v.y);
        tile[rr][c0 + j * 4 + 2] = (unsigned short)bf16_rne(v.z);
        tile[rr][c0 + j * 4 + 3] = (unsigned short)bf16_rne(v.w);
    }
    __syncthreads();
    const int nr = tt >> 2, kc = (tt & 3) * 16;
    unsigned short* dst = T + (size_t)(n0 + nr) * K + k0 + kc;
    ushort4 o;
#pragma unroll
    for (int j = 0; j < 4; ++j) {
        o.x = tile[kc + j * 4 + 0][nr];
        o.y = tile[kc + j * 4 + 1][nr];
        o.z = tile[kc + j * 4 + 2][nr];
        o.w = tile[kc + j * 4 + 3][nr];
        *(ushort4*)(dst + j * 4) = o;
    }
}

// ---------------------------------------------------------------------------
// bf16 GEMM core, BK=32, 1D XCD-swizzled grid (by = bid%64 -> same-panel
// blocks share an XCD; 64%8==0). 128x128 tile, 256 thr.
// OMODE: 0 = fp32 direct stores, 1 = bf16 via LDS-roundtrip coalesced stores.
// ---------------------------------------------------------------------------
template <int OMODE>
__global__ __launch_bounds__(256)
void gemm_bt(const unsigned short* __restrict__ A, const unsigned short* __restrict__ Bt,
             const float* __restrict__ bias, void* __restrict__ Cv,
             int N, int K, int gelu) {
    __shared__ __align__(16) unsigned short smem[8704];   // 17.4 KB (epilogue 64x136)
    unsigned short* sA = smem;
    unsigned short* sB = smem + 4096;
    const int tid = threadIdx.x, lane = tid & 63, wid = tid >> 6;
    const int bid = blockIdx.x;
    const int row0 = (bid & 63) * 128, col0 = (bid >> 6) * 128;
    const int rh = (wid >> 1) * 64, ch = (wid & 1) * 64;
    const int fr = lane & 15, fq = lane >> 4;
    const int srow = wid * 32 + (lane >> 2);
    const int skoff = (lane & 3) * 8;
    const unsigned short* gA0 = A + (size_t)(row0 + srow) * K + skoff;
    const unsigned short* gA1 = gA0 + (size_t)16 * K;
    const unsigned short* gB0 = Bt + (size_t)(col0 + srow) * K + skoff;
    const unsigned short* gB1 = gB0 + (size_t)16 * K;
    lds_u32* lA0 = (lds_u32*)&sA[wid * 1024];
    lds_u32* lA1 = (lds_u32*)&sA[wid * 1024 + 512];
    lds_u32* lB0 = (lds_u32*)&sB[wid * 1024];
    lds_u32* lB1 = (lds_u32*)&sB[wid * 1024 + 512];

    f32x4 acc[4][4] = {};
    for (int k0 = 0; k0 < K; k0 += 32) {
        __syncthreads();
        __builtin_amdgcn_global_load_lds((ga_u32*)(gA0 + k0), lA0, 16, 0, 0);
        __builtin_amdgcn_global_load_lds((ga_u32*)(gA1 + k0), lA1, 16, 0, 0);
        __builtin_amdgcn_global_load_lds((ga_u32*)(gB0 + k0), lB0, 16, 0, 0);
        __builtin_amdgcn_global_load_lds((ga_u32*)(gB1 + k0), lB1, 16, 0, 0);
        __syncthreads();
        s16x8 af[4], bf[4];
#pragma unroll
        for (int i = 0; i < 4; ++i)
            af[i] = *(const s16x8*)&sA[(rh + 16 * i + fr) * 32 + fq * 8];
#pragma unroll
        for (int j = 0; j < 4; ++j)
            bf[j] = *(const s16x8*)&sB[(ch + 16 * j + fr) * 32 + fq * 8];
#pragma unroll
        for (int i = 0; i < 4; ++i)
#pragma unroll
            for (int j = 0; j < 4; ++j)
                acc[i][j] = __builtin_amdgcn_mfma_f32_16x16x32_bf16(af[i], bf[j], acc[i][j], 0, 0, 0);
    }
    if (OMODE == 0) {
#pragma unroll
        for (int j = 0; j < 4; ++j) {
            int col = col0 + ch + 16 * j + fr;
            float bb = bias[col];
#pragma unroll
            for (int i = 0; i < 4; ++i)
#pragma unroll
                for (int r = 0; r < 4; ++r) {
                    int row = row0 + rh + 16 * i + fq * 4 + r;
                    float v = acc[i][j][r] + bb;
                    if (gelu) v = gelu_fast(v);
                    ((float*)Cv)[(size_t)row * N + col] = v;
                }
        }
    } else {
        unsigned short* sC = smem;   // 64 rows x stride 136 = 8704 u16
#pragma unroll
        for (int hh = 0; hh < 2; ++hh) {
            __syncthreads();
            if ((wid >> 1) == hh) {
#pragma unroll
                for (int j = 0; j < 4; ++j) {
                    float bb = bias[col0 + ch + 16 * j + fr];
#pragma unroll
                    for (int i = 0; i < 4; ++i)
#pragma unroll
                        for (int r = 0; r < 4; ++r) {
                            float v = acc[i][j][r] + bb;
                            if (gelu) v = gelu_fast(v);
                            sC[(16 * i + fq * 4 + r) * 136 + ch + 16 * j + fr] =
                                (unsigned short)bf16_rne(v);
                        }
                }
            }
            __syncthreads();
#pragma unroll
            for (int p = 0; p < 4; ++p) {
                int seg = p * 256 + tid;
                int r = seg >> 4, c8 = (seg & 15) * 8;
                *(u16x8*)&((unsigned short*)Cv)[(size_t)(row0 + hh * 64 + r) * N + col0 + c8] =
                    *(const u16x8*)&sC[r * 136 + c8];
            }
        }
    }
}

// Fused QKV GEMM (BK=32, swizzled 1D grid of 18*64): seg 0 -> Qh, 1 -> Kh
// (LDS-roundtrip bf16), 2 -> VT transposed ushort4 stores.
__global__ __launch_bounds__(256)
void gemm_qkv(const unsigned short* __restrict__ A, const unsigned short* __restrict__ Bt,
              const float* __restrict__ bq, const float* __restrict__ bk,
              const float* __restrict__ bv,
              unsigned short* __restrict__ Qh, unsigned short* __restrict__ Kh,
              unsigned short* __restrict__ VT) {
    const int K = D_;
    __shared__ __align__(16) unsigned short smem[8704];
    unsigned short* sA = smem;
    unsigned short* sB = smem + 4096;
    const int tid = threadIdx.x, lane = tid & 63, wid = tid >> 6;
    const int bid = blockIdx.x;
    const int row0 = (bid & 63) * 128;
    const int bx = bid >> 6;
    const int col0 = bx * 128;
    const int rh = (wid >> 1) * 64, ch = (wid & 1) * 64;
    const int fr = lane & 15, fq = lane >> 4;
    const int srow = wid * 32 + (lane >> 2);
    const int skoff = (lane & 3) * 8;
    const unsigned short* gA0 = A + (size_t)(row0 + srow) * K + skoff;
    const unsigned short* gA1 = gA0 + (size_t)16 * K;
    const unsigned short* gB0 = Bt + (size_t)(col0 + srow) * K + skoff;
    const unsigned short* gB1 = gB0 + (size_t)16 * K;
    lds_u32* lA0 = (lds_u32*)&sA[wid * 1024];
    lds_u32* lA1 = (lds_u32*)&sA[wid * 1024 + 512];
    lds_u32* lB0 = (lds_u32*)&sB[wid * 1024];
    lds_u32* lB1 = (lds_u32*)&sB[wid * 1024 + 512];

    f32x4 acc[4][4] = {};
    for (int k0 = 0; k0 < K; k0 += 32) {
        __syncthreads();
        __builtin_amdgcn_global_load_lds((ga_u32*)(gA0 + k0), lA0, 16, 0, 0);
        __builtin_amdgcn_global_load_lds((ga_u32*)(gA1 + k0), lA1, 16, 0, 0);
        __builtin_amdgcn_global_load_lds((ga_u32*)(gB0 + k0), lB0, 16, 0, 0);
        __builtin_amdgcn_global_load_lds((ga_u32*)(gB1 + k0), lB1, 16, 0, 0);
        __syncthreads();
        s16x8 af[4], bf[4];
#pragma unroll
        for (int i = 0; i < 4; ++i)
            af[i] = *(const s16x8*)&sA[(rh + 16 * i + fr) * 32 + fq * 8];
#pragma unroll
        for (int j = 0; j < 4; ++j)
            bf[j] = *(const s16x8*)&sB[(ch + 16 * j + fr) * 32 + fq * 8];
#pragma unroll
        for (int i = 0; i < 4; ++i)
#pragma unroll
            for (int j = 0; j < 4; ++j)
                acc[i][j] = __builtin_amdgcn_mfma_f32_16x16x32_bf16(af[i], bf[j], acc[i][j], 0, 0, 0);
    }
    const int seg = bx / 6;
    const int colbase = col0 - seg * D_;
    const float* bias = (seg == 0) ? bq : (seg == 1) ? bk : bv;
    if (seg == 2) {
#pragma unroll
        for (int j = 0; j < 4; ++j) {
            int col_l = colbase + ch + 16 * j + fr;
            float bb = bias[col_l];
#pragma unroll
            for (int i = 0; i < 4; ++i) {
                int rowbase = row0 + rh + 16 * i + fq * 4;
                ushort4 o;
                o.x = (unsigned short)bf16_rne(acc[i][j][0] + bb);
                o.y = (unsigned short)bf16_rne(acc[i][j][1] + bb);
                o.z = (unsigned short)bf16_rne(acc[i][j][2] + bb);
                o.w = (unsigned short)bf16_rne(acc[i][j][3] + bb);
                *(ushort4*)&VT[(size_t)col_l * ROWS_ + rowbase] = o;
            }
        }
    } else {
        unsigned short* dst = (seg == 0) ? Qh : Kh;
        unsigned short* sC = smem;
#pragma unroll
        for (int hh = 0; hh < 2; ++hh) {
            __syncthreads();
            if ((wid >> 1) == hh) {
#pragma unroll
                for (int j = 0; j < 4; ++j) {
                    float bb = bias[colbase + ch + 16 * j + fr];
#pragma unroll
                    for (int i = 0; i < 4; ++i)
#pragma unroll
                        for (int r = 0; r < 4; ++r)
                            sC[(16 * i + fq * 4 + r) * 136 + ch + 16 * j + fr] =
                                (unsigned short)bf16_rne(acc[i][j][r] + bb);
                }
            }
            __syncthreads();
#pragma unroll
            for (int p = 0; p < 4; ++p) {
                int seg2 = p * 256 + tid;
                int r = seg2 >> 4, c8 = (seg2 & 15) * 8;
                *(u16x8*)&dst[(size_t)(row0 + hh * 64 + r) * D_ + colbase + c8] =
                    *(const u16x8*)&sC[r * 136 + c8];
            }
        }
    }
}

// ---------------------------------------------------------------------------
// bf16 MFMA block-sparse attention (verified round 3, unchanged).
// ---------------------------------------------------------------------------
template <bool EDGE>
__global__ __launch_bounds__(256, 4)
void attn_mfma(const unsigned short* __restrict__ Qb, const unsigned short* __restrict__ Kb,
               const unsigned short* __restrict__ VTb, const int* __restrict__ rb,
               unsigned short* __restrict__ ctx, float* __restrict__ scratch) {
    __shared__ __align__(16) unsigned short sQ[64][72];
    __shared__ __align__(16) unsigned short sK[64][72];
    __shared__ __align__(16) unsigned short sVT[64][72];
    __shared__ __align__(16) unsigned short sP[4][16][72];
    __shared__ int sList[16];
    const int tid = threadIdx.x, lane = tid & 63, wid = tid >> 6;
    const int fr = lane & 15, fq = lane >> 4;
    int qb, h, b, nkb, slice = 0;
    if (EDGE) {
        int part = blockIdx.x & 3;
        int hh = (blockIdx.x >> 2) % H_;
        int be = (blockIdx.x >> 2) / H_;
        int eb = be & 1;
        b = be >> 1;
        h = hh;
        qb = eb ? (NB_ - 1) : 0;
        nkb = 16;
        slice = ((b * 2 + eb) * H_ + h) * 4 + part;
        if (tid < 16) sList[tid] = part * 16 + tid;
    } else {
        qb = blockIdx.x % (NB_ - 2) + 1;
        h = (blockIdx.x / (NB_ - 2)) % H_;
        b = blockIdx.x / ((NB_ - 2) * H_);
        nkb = 8;
        if (tid < 8) {
            int e;
            if (tid == 0) e = 0;
            else if (tid == 1) e = NB_ - 1;
            else if (tid < 5) e = qb + (tid - 3);
            else e = rb[(h * NB_ + qb) * 3 + (tid - 5)];
            sList[tid] = e;
        }
    }
    const int qrow0 = b * N_ + qb * 64;
    const unsigned short* Qg = Qb + (size_t)qrow0 * D_ + h * 64;
#pragma unroll
    for (int p = 0; p < 2; ++p) {
        int idx = p * 256 + tid;
        int r = idx >> 3, o = (idx & 7) * 8;
        *(u16x8*)&sQ[r][o] = *(const u16x8*)(Qg + (size_t)r * D_ + o);
    }
    f32x4 oacc[4] = {};
    float l_part[4] = {};
    __syncthreads();
    s16x8 aq0 = *(const s16x8*)&sQ[wid * 16 + fr][fq * 8];
    s16x8 aq1 = *(const s16x8*)&sQ[wid * 16 + fr][32 + fq * 8];

    for (int kb = 0; kb < nkb; ++kb) {
        const int kblk = sList[kb];
        const int keyrow0 = b * N_ + kblk * 64;
        __syncthreads();
        const unsigned short* Kg = Kb + (size_t)keyrow0 * D_ + h * 64;
#pragma unroll
        for (int p = 0; p < 2; ++p) {
            int idx = p * 256 + tid;
            int r = idx >> 3, o = (idx & 7) * 8;
            *(u16x8*)&sK[r][o] = *(const u16x8*)(Kg + (size_t)r * D_ + o);
        }
        const unsigned short* Vg = VTb + (size_t)(h * 64) * ROWS_ + keyrow0;
#pragma unroll
        for (int p = 0; p < 2; ++p) {
            int idx = p * 256 + tid;
            int d = idx >> 3, o = (idx & 7) * 8;
            *(u16x8*)&sVT[d][o] = *(const u16x8*)(Vg + (size_t)d * ROWS_ + o);
        }
        __syncthreads();
#pragma unroll
        for (int g = 0; g < 4; ++g) {
            s16x8 bk0 = *(const s16x8*)&sK[g * 16 + fr][fq * 8];
            s16x8 bk1 = *(const s16x8*)&sK[g * 16 + fr][32 + fq * 8];
            f32x4 s = {};
            s = __builtin_amdgcn_mfma_f32_16x16x32_bf16(aq0, bk0, s, 0, 0, 0);
            s = __builtin_amdgcn_mfma_f32_16x16x32_bf16(aq1, bk1, s, 0, 0, 0);
#pragma unroll
            for (int r = 0; r < 4; ++r) {
                float pv = __expf(s[r] * 0.125f);
                l_part[r] += pv;
                sP[wid][fq * 4 + r][g * 16 + fr] = (unsigned short)bf16_rne(pv);
            }
        }
        s16x8 ap0 = *(const s16x8*)&sP[wid][fr][fq * 8];
        s16x8 ap1 = *(const s16x8*)&sP[wid][fr][32 + fq * 8];
#pragma unroll
        for (int g = 0; g < 4; ++g) {
            s16x8 bv0 = *(const s16x8*)&sVT[g * 16 + fr][fq * 8];
            s16x8 bv1 = *(const s16x8*)&sVT[g * 16 + fr][32 + fq * 8];
            oacc[g] = __builtin_amdgcn_mfma_f32_16x16x32_bf16(ap0, bv0, oacc[g], 0, 0, 0);
            oacc[g] = __builtin_amdgcn_mfma_f32_16x16x32_bf16(ap1, bv1, oacc[g], 0, 0, 0);
        }
    }
    float l4[4];
#pragma unroll
    for (int r = 0; r < 4; ++r) {
        float lv = l_part[r];
        lv += __shfl_xor(lv, 1, 64);
        lv += __shfl_xor(lv, 2, 64);
        lv += __shfl_xor(lv, 4, 64);
        lv += __shfl_xor(lv, 8, 64);
        l4[r] = lv;
    }
    if (EDGE) {
        float* sc = scratch + (size_t)slice * (64 * 64 + 64);
#pragma unroll
        for (int g = 0; g < 4; ++g)
#pragma unroll
            for (int r = 0; r < 4; ++r)
                sc[(wid * 16 + fq * 4 + r) * 64 + g * 16 + fr] = oacc[g][r];
        if (fr == 0) {
#pragma unroll
            for (int r = 0; r < 4; ++r)
                sc[4096 + wid * 16 + fq * 4 + r] = l4[r];
        }
    } else {
        __syncthreads();
#pragma unroll
        for (int g = 0; g < 4; ++g) {
#pragma unroll
            for (int r = 0; r < 4; ++r) {
                float v = oacc[g][r] / l4[r];
                sK[wid * 16 + fq * 4 + r][g * 16 + fr] = (unsigned short)bf16_rne(v);
            }
        }
        __syncthreads();
        unsigned short* Cg = ctx + (size_t)qrow0 * D_ + h * 64;
#pragma unroll
        for (int p = 0; p < 2; ++p) {
            int idx = p * 256 + tid;
            int r = idx >> 3, o = (idx & 7) * 8;
            *(u16x8*)(Cg + (size_t)r * D_ + o) = *(const u16x8*)&sK[r][o];
        }
    }
}

__global__ __launch_bounds__(256)
void edge_combine(const float* __restrict__ scratch, unsigned short* __restrict__ ctx) {
    const int bid = blockIdx.x;
    const int h = bid % H_;
    const int eb = (bid / H_) & 1;
    const int b = bid / (2 * H_);
    const int qb = eb ? (NB_ - 1) : 0;
    const int qrow0 = b * N_ + qb * 64;
    const int slice0 = bid * 4;
    for (int e = threadIdx.x; e < 4096; e += 256) {
        int row = e >> 6, col = e & 63;
        float o = 0.f, l = 0.f;
#pragma unroll
        for (int p = 0; p < 4; ++p) {
            const float* sc = scratch + (size_t)(slice0 + p) * (64 * 64 + 64);
            o += sc[row * 64 + col];
            l += sc[4096 + row];
        }
        ctx[(size_t)(qrow0 + row) * D_ + h * 64 + col] = (unsigned short)bf16_rne(o / l);
    }
}

// ---------------------------------------------------------------------------
// LayerNorm — bf16 residual stream, fp32 math.
// ---------------------------------------------------------------------------
__global__ __launch_bounds__(256)
void embed_ln_kernel(const float* __restrict__ emb, const float* __restrict__ pos,
                     const float* __restrict__ tt, const float* __restrict__ g,
                     const float* __restrict__ bb, unsigned short* __restrict__ out) {
    __shared__ float red1[4], red2[4];
    const int row = blockIdx.x;
    const int n = row & (N_ - 1);
    const int t = threadIdx.x;
    float v[3];
#pragma unroll
    for (int i = 0; i < 3; ++i) {
        int d = t + i * 256;
        v[i] = emb[(size_t)row * D_ + d] + pos[(size_t)n * D_ + d] + tt[d];
    }
    float s = v[0] + v[1] + v[2];
#pragma unroll
    for (int off = 32; off > 0; off >>= 1) s += __shfl_xor(s, off, 64);
    if ((t & 63) == 0) red1[t >> 6] = s;
    __syncthreads();
    float mu = (red1[0] + red1[1] + red1[2] + red1[3]) * (1.0f / D_);
    float q = 0;
#pragma unroll
    for (int i = 0; i < 3; ++i) { float dv = v[i] - mu; q += dv * dv; }
#pragma unroll
    for (int off = 32; off > 0; off >>= 1) q += __shfl_xor(q, off, 64);
    if ((t & 63) == 0) red2[t >> 6] = q;
    __syncthreads();
    float var = (red2[0] + red2[1] + red2[2] + red2[3]) * (1.0f / D_);
    float rs = rsqrtf(var + 1e-12f);
#pragma unroll
    for (int i = 0; i < 3; ++i) {
        int d = t + i * 256;
        out[(size_t)row * D_ + d] = (unsigned short)bf16_rne((v[i] - mu) * rs * g[d] + bb[d]);
    }
}

__global__ __launch_bounds__(256)
void add_ln_kernel(const unsigned short* __restrict__ X, const float* __restrict__ Y,
                   const float* __restrict__ g, const float* __restrict__ bb,
                   unsigned short* __restrict__ out) {
    __shared__ float red1[4], red2[4];
    const int row = blockIdx.x;
    const int t = threadIdx.x;
    float v[3];
#pragma unroll
    for (int i = 0; i < 3; ++i) {
        int d = t + i * 256;
        v[i] = bfh2f(X[(size_t)row * D_ + d]) + Y[(size_t)row * D_ + d];
    }
    float s = v[0] + v[1] + v[2];
#pragma unroll
    for (int off = 32; off > 0; off >>= 1) s += __shfl_xor(s, off, 64);
    if ((t & 63) == 0) red1[t >> 6] = s;
    __syncthreads();
    float mu = (red1[0] + red1[1] + red1[2] + red1[3]) * (1.0f / D_);
    float q = 0;
#pragma unroll
    for (int i = 0; i < 3; ++i) { float dv = v[i] - mu; q += dv * dv; }
#pragma unroll
    for (int off = 32; off > 0; off >>= 1) q += __shfl_xor(q, off, 64);
    if ((t & 63) == 0) red2[t >> 6] = q;
    __syncthreads();
    float var = (red2[0] + red2[1] + red2[2] + red2[3]) * (1.0f / D_);
    float rs = rsqrtf(var + 1e-12f);
#pragma unroll
    for (int i = 0; i < 3; ++i) {
        int d = t + i * 256;
        out[(size_t)row * D_ + d] = (unsigned short)bf16_rne((v[i] - mu) * rs * g[d] + bb[d]);
    }
}

// ---------------------------------------------------------------------------
// Mean-pool over N then fc
// ---------------------------------------------------------------------------
__global__ __launch_bounds__(256)
void pool_partial_kernel(const unsigned short* __restrict__ X, float* __restrict__ partial) {
    int blk = blockIdx.x;
    int b = blk >> 4, c = blk & 15;
    int t = threadIdx.x;
#pragma unroll
    for (int i = 0; i < 3; ++i) {
        int d = t + i * 256;
        float s = 0.f;
        for (int n = 0; n < 256; ++n)
            s += bfh2f(X[((size_t)(b * N_ + c * 256 + n)) * D_ + d]);
        partial[(size_t)(b * 16 + c) * D_ + d] = s;
    }
}

__global__ __launch_bounds__(256)
void pool_final_kernel(const float* __restrict__ partial, const float* __restrict__ fcw,
                       const float* __restrict__ fcb, float* __restrict__ out) {
    __shared__ float red[4];
    int t = threadIdx.x;
    for (int b = 0; b < B_; ++b) {
        float s = 0.f;
#pragma unroll
        for (int i = 0; i < 3; ++i) {
            int d = t + i * 256;
            float ps = 0.f;
#pragma unroll
            for (int c = 0; c < 16; ++c) ps += partial[(size_t)(b * 16 + c) * D_ + d];
            s += ps * (1.0f / N_) * fcw[d];
        }
#pragma unroll
        for (int off = 32; off > 0; off >>= 1) s += __shfl_xor(s, off, 64);
        __syncthreads();
        if ((t & 63) == 0) red[t >> 6] = s;
        __syncthreads();
        if (t == 0) out[b] = red[0] + red[1] + red[2] + red[3] + fcb[0];
    }
}

// ---------------------------------------------------------------------------
extern "C" void kernel_launch(void* const* d_in, const int* in_sizes, int n_in,
                              void* d_out, int out_size, void* d_ws, size_t ws_size,
                              hipStream_t stream) {
    (void)in_sizes; (void)n_in; (void)out_size; (void)ws_size;
    const float* emb  = (const float*)d_in[0];
    const int*   rblk = (const int*)d_in[1];
    const float* pos  = (const float*)d_in[2];
    const float* tt   = (const float*)d_in[3];
    const float* elg  = (const float*)d_in[4];
    const float* elb  = (const float*)d_in[5];
    const float* Wq   = (const float*)d_in[6];
    const float* bq   = (const float*)d_in[7];
    const float* Wk   = (const float*)d_in[8];
    const float* bk   = (const float*)d_in[9];
    const float* Wv   = (const float*)d_in[10];
    const float* bv   = (const float*)d_in[11];
    const float* Wo   = (const float*)d_in[12];
    const float* bo   = (const float*)d_in[13];
    const float* ln1g = (const float*)d_in[14];
    const float* ln1b = (const float*)d_in[15];
    const float* Wi   = (const float*)d_in[16];
    const float* bi   = (const float*)d_in[17];
    const float* Wd   = (const float*)d_in[18];
    const float* bd   = (const float*)d_in[19];
    const float* ln2g = (const float*)d_in[20];
    const float* ln2b = (const float*)d_in[21];
    const float* fcw  = (const float*)d_in[22];
    const float* fcb  = (const float*)d_in[23];
    float* outp = (float*)d_out;

    const size_t R = (size_t)ROWS_ * D_;          // 6,291,456
    float* base = (float*)d_ws;
    unsigned short* Xh  = (unsigned short*)base;
    unsigned short* Abh = (unsigned short*)(base + R / 2);
    float* G32 = base + R;
    unsigned short* Qh  = (unsigned short*)(base + 2 * R);
    unsigned short* Kh  = (unsigned short*)(base + 2 * R + R / 2);
    unsigned short* VTh = (unsigned short*)(base + 3 * R);
    unsigned short* Ch  = (unsigned short*)(base + 3 * R + R / 2);
    unsigned short* Hh  = (unsigned short*)(base + 2 * R);    // FFN hidden overlays QKVC
    unsigned short* Wt  = (unsigned short*)(base + 4 * R);
    float* Esc = base + 4 * R + 7077888;
    float* Pp  = Esc + 798720;

    const size_t LW = 7077888;
    const int rows = ROWS_;
    dim3 blk(256);

    prep_weights<<<2 * 1728, blk, 0, stream>>>(Wq, Wk, Wv, Wo, Wi, Wd, Wt);

    embed_ln_kernel<<<rows, blk, 0, stream>>>(emb, pos, tt, elg, elb, Xh);

    for (int l = 0; l < LAYERS_; ++l) {
        const float* bq_l = bq + (size_t)l * D_;
        const float* bk_l = bk + (size_t)l * D_;
        const float* bv_l = bv + (size_t)l * D_;
        const float* bo_l = bo + (size_t)l * D_;
        const float* bi_l = bi + (size_t)l * FF_;
        const float* bd_l = bd + (size_t)l * D_;
        const float* l1g = ln1g + (size_t)l * D_;
        const float* l1b = ln1b + (size_t)l * D_;
        const float* l2g = ln2g + (size_t)l * D_;
        const float* l2b = ln2b + (size_t)l * D_;
        const int* rb_l = rblk + (size_t)l * H_ * NB_ * 3;
        unsigned short* QKVt = Wt + l * LW;
        unsigned short* Ot = QKVt + 2304 * 768;
        unsigned short* It = Ot + 768 * 768;
        unsigned short* Dt = It + 3072 * 768;

        gemm_qkv<<<18 * 64, blk, 0, stream>>>(Xh, QKVt, bq_l, bk_l, bv_l, Qh, Kh, VTh);

        attn_mfma<false><<<B_ * H_ * (NB_ - 2), blk, 0, stream>>>(Qh, Kh, VTh, rb_l, Ch, Esc);
        attn_mfma<true><<<B_ * 2 * H_ * 4, blk, 0, stream>>>(Qh, Kh, VTh, rb_l, Ch, Esc);
        edge_combine<<<B_ * 2 * H_, blk, 0, stream>>>(Esc, Ch);

        gemm_bt<0><<<6 * 64, blk, 0, stream>>>(Ch, Ot, bo_l, G32, D_, D_, 0);
        add_ln_kernel<<<rows, blk, 0, stream>>>(Xh, G32, l1g, l1b, Abh);

        gemm_bt<1><<<24 * 64, blk, 0, stream>>>(Abh, It, bi_l, Hh, FF_, D_, 1);
        gemm_bt<0><<<6 * 64, blk, 0, stream>>>(Hh, Dt, bd_l, G32, D_, FF_, 0);

        add_ln_kernel<<<rows, blk, 0, stream>>>(Abh, G32, l2g, l2b, Xh);
    }

    pool_partial_kernel<<<B_ * 16, blk, 0, stream>>>(Xh, Pp);
    pool_final_kernel<<<1, blk, 0, stream>>>(Pp, fcw, fcb, outp);
}

// Round 7
// 754.253 us; speedup vs baseline: 1.2848x; 1.1014x over previous
//
#include <hip/hip_runtime.h>
#include <math.h>

#define B_ 2
#define N_ 4096
#define D_ 768
#define H_ 12
#define DH_ 64
#define NB_ 64
#define FF_ 3072
#define LAYERS_ 2
#define ROWS_ (B_ * N_)   // 8192

typedef __attribute__((ext_vector_type(8))) short s16x8;            // bf16x8 frag
typedef __attribute__((ext_vector_type(8))) unsigned short u16x8;   // staging
typedef __attribute__((ext_vector_type(4))) float f32x4;

typedef const __attribute__((address_space(1))) unsigned int ga_u32;
typedef __attribute__((address_space(3))) unsigned int lds_u32;

static __device__ __forceinline__ float gelu_fast(float x) {
    // 0.5x(1+tanh(z)) == x*sigmoid(2z), z = sqrt(2/pi)(x+0.044715x^3)
    float z2 = 1.5957691216057308f * x * (1.0f + 0.044715f * x * x);
    return x * __builtin_amdgcn_rcpf(1.0f + __expf(-z2));
}

static __device__ __forceinline__ unsigned bf16_rne(float f) {
    unsigned u = __float_as_uint(f);
    return (u + 0x7FFFu + ((u >> 16) & 1u)) >> 16;
}
static __device__ __forceinline__ float bfh2f(unsigned short h) {
    return __uint_as_float(((unsigned)h) << 16);
}

// ---------------------------------------------------------------------------
// Weight prep, all transposes in ONE launch. Each block: one 64x64 tile.
// Layout per layer in Wt: [Q^T 768x768][K^T][V^T][O^T][I^T 3072x768][D^T 768x3072]
// ---------------------------------------------------------------------------
__global__ __launch_bounds__(256)
void prep_weights(const float* __restrict__ Wq, const float* __restrict__ Wk,
                  const float* __restrict__ Wv, const float* __restrict__ Wo,
                  const float* __restrict__ Wi, const float* __restrict__ Wd,
                  unsigned short* __restrict__ Wt) {
    const size_t LW = 7077888;
    int bid = blockIdx.x;
    int l = bid / 1728, r = bid % 1728;
    const float* W; unsigned short* T; int K, N, t, nx;
    if (r < 576) {
        int which = r / 144; t = r % 144; nx = 12; K = 768; N = 768;
        W = (which == 0 ? Wq : which == 1 ? Wk : which == 2 ? Wv : Wo) + (size_t)l * D_ * D_;
        T = Wt + l * LW + (size_t)(which < 3 ? which * 768 * 768 : 2304 * 768);
    } else if (r < 1152) {
        t = r - 576; nx = 48; K = 768; N = 3072;
        W = Wi + (size_t)l * D_ * FF_;
        T = Wt + l * LW + (size_t)(2304 * 768 + 768 * 768);
    } else {
        t = r - 1152; nx = 12; K = 3072; N = 768;
        W = Wd + (size_t)l * FF_ * D_;
        T = Wt + l * LW + (size_t)(2304 * 768 + 768 * 768 + 3072 * 768);
    }
    const int bx = t % nx, by = t / nx;
    __shared__ unsigned short tile[64][72];
    const int k0 = by * 64, n0 = bx * 64;
    const int tt = threadIdx.x;
    const int rr = tt >> 2, c0 = (tt & 3) * 16;
    const float* src = W + (size_t)(k0 + rr) * N + n0 + c0;
#pragma unroll
    for (int j = 0; j < 4; ++j) {
        float4 v = *(const float4*)(src + j * 4);
        tile[rr][c0 + j * 4 + 0] = (unsigned short)bf16_rne(v.x);
        tile[rr][c0 + j * 4 + 1] = (unsigned short)bf16_rne(v.y);
        tile[rr][c0 + j * 4 + 2] = (unsigned short)bf16_rne(v.z);
        tile[rr][c0 + j * 4 + 3] = (unsigned short)bf16_rne(v.w);
    }
    __syncthreads();
    const int nr = tt >> 2, kc = (tt & 3) * 16;
    unsigned short* dst = T + (size_t)(n0 + nr) * K + k0 + kc;
    ushort4 o;
#pragma unroll
    for (int j = 0; j < 4; ++j) {
        o.x = tile[kc + j * 4 + 0][nr];
        o.y = tile[kc + j * 4 + 1][nr];
        o.z = tile[kc + j * 4 + 2][nr];
        o.w = tile[kc + j * 4 + 3][nr];
        *(ushort4*)(dst + j * 4) = o;
    }
}

// ---------------------------------------------------------------------------
// bf16 GEMM core, BK=32, DOUBLE-BUFFERED (one barrier/iter; prefetch issued
// right after the barrier, lands during the MFMA phase). 1D XCD-swizzled grid
// (row panel = bid%64 -> per-XCD A partitioning). 128x128 tile, 256 thr.
// OMODE: 0 = fp32 direct stores, 1 = bf16 via LDS-roundtrip coalesced stores.
// ---------------------------------------------------------------------------
template <int OMODE>
__global__ __launch_bounds__(256)
void gemm_bt(const unsigned short* __restrict__ A, const unsigned short* __restrict__ Bt,
             const float* __restrict__ bias, void* __restrict__ Cv,
             int N, int K, int gelu) {
    __shared__ __align__(16) unsigned short smem[2 * 8192];   // 2 x (4K A + 4K B) u16 = 32 KB
    const int tid = threadIdx.x, lane = tid & 63, wid = tid >> 6;
    const int bid = blockIdx.x;
    const int row0 = (bid & 63) * 128, col0 = (bid >> 6) * 128;
    const int rh = (wid >> 1) * 64, ch = (wid & 1) * 64;
    const int fr = lane & 15, fq = lane >> 4;
    const int srow = wid * 32 + (lane >> 2);
    const int skoff = (lane & 3) * 8;
    const unsigned short* gA0 = A + (size_t)(row0 + srow) * K + skoff;
    const unsigned short* gA1 = gA0 + (size_t)16 * K;
    const unsigned short* gB0 = Bt + (size_t)(col0 + srow) * K + skoff;
    const unsigned short* gB1 = gB0 + (size_t)16 * K;

    f32x4 acc[4][4] = {};
    const int nk = K >> 5;

    // prologue: tile 0 -> buffer 0
    {
        unsigned short* s = smem;
        __builtin_amdgcn_global_load_lds((ga_u32*)gA0, (lds_u32*)&s[wid * 1024], 16, 0, 0);
        __builtin_amdgcn_global_load_lds((ga_u32*)gA1, (lds_u32*)&s[wid * 1024 + 512], 16, 0, 0);
        __builtin_amdgcn_global_load_lds((ga_u32*)gB0, (lds_u32*)&s[4096 + wid * 1024], 16, 0, 0);
        __builtin_amdgcn_global_load_lds((ga_u32*)gB1, (lds_u32*)&s[4096 + wid * 1024 + 512], 16, 0, 0);
    }
    for (int kt = 0; kt < nk; ++kt) {
        __syncthreads();   // drains tile-kt loads (issued one full iteration ago)
        if (kt + 1 < nk) { // prefetch tile kt+1 into the other buffer
            int k0 = (kt + 1) << 5;
            unsigned short* s = smem + ((kt + 1) & 1) * 8192;
            __builtin_amdgcn_global_load_lds((ga_u32*)(gA0 + k0), (lds_u32*)&s[wid * 1024], 16, 0, 0);
            __builtin_amdgcn_global_load_lds((ga_u32*)(gA1 + k0), (lds_u32*)&s[wid * 1024 + 512], 16, 0, 0);
            __builtin_amdgcn_global_load_lds((ga_u32*)(gB0 + k0), (lds_u32*)&s[4096 + wid * 1024], 16, 0, 0);
            __builtin_amdgcn_global_load_lds((ga_u32*)(gB1 + k0), (lds_u32*)&s[4096 + wid * 1024 + 512], 16, 0, 0);
        }
        const unsigned short* sA = smem + (kt & 1) * 8192;
        const unsigned short* sB = sA + 4096;
        s16x8 af[4], bf[4];
#pragma unroll
        for (int i = 0; i < 4; ++i)
            af[i] = *(const s16x8*)&sA[(rh + 16 * i + fr) * 32 + fq * 8];
#pragma unroll
        for (int j = 0; j < 4; ++j)
            bf[j] = *(const s16x8*)&sB[(ch + 16 * j + fr) * 32 + fq * 8];
#pragma unroll
        for (int i = 0; i < 4; ++i)
#pragma unroll
            for (int j = 0; j < 4; ++j)
                acc[i][j] = __builtin_amdgcn_mfma_f32_16x16x32_bf16(af[i], bf[j], acc[i][j], 0, 0, 0);
    }
    if (OMODE == 0) {
#pragma unroll
        for (int j = 0; j < 4; ++j) {
            int col = col0 + ch + 16 * j + fr;
            float bb = bias[col];
#pragma unroll
            for (int i = 0; i < 4; ++i)
#pragma unroll
                for (int r = 0; r < 4; ++r) {
                    int row = row0 + rh + 16 * i + fq * 4 + r;
                    float v = acc[i][j][r] + bb;
                    if (gelu) v = gelu_fast(v);
                    ((float*)Cv)[(size_t)row * N + col] = v;
                }
        }
    } else {
        unsigned short* sC = smem;   // 64 rows x stride 136 = 8704 u16 (fits)
#pragma unroll
        for (int hh = 0; hh < 2; ++hh) {
            __syncthreads();
            if ((wid >> 1) == hh) {
#pragma unroll
                for (int j = 0; j < 4; ++j) {
                    float bb = bias[col0 + ch + 16 * j + fr];
#pragma unroll
                    for (int i = 0; i < 4; ++i)
#pragma unroll
                        for (int r = 0; r < 4; ++r) {
                            float v = acc[i][j][r] + bb;
                            if (gelu) v = gelu_fast(v);
                            sC[(16 * i + fq * 4 + r) * 136 + ch + 16 * j + fr] =
                                (unsigned short)bf16_rne(v);
                        }
                }
            }
            __syncthreads();
#pragma unroll
            for (int p = 0; p < 4; ++p) {
                int seg = p * 256 + tid;
                int r = seg >> 4, c8 = (seg & 15) * 8;
                *(u16x8*)&((unsigned short*)Cv)[(size_t)(row0 + hh * 64 + r) * N + col0 + c8] =
                    *(const u16x8*)&sC[r * 136 + c8];
            }
        }
    }
}

// Fused QKV GEMM (BK=32, double-buffered, swizzled 1D grid of 18*64):
// seg 0 -> Qh, 1 -> Kh (LDS-roundtrip bf16), 2 -> VT transposed ushort4.
__global__ __launch_bounds__(256)
void gemm_qkv(const unsigned short* __restrict__ A, const unsigned short* __restrict__ Bt,
              const float* __restrict__ bq, const float* __restrict__ bk,
              const float* __restrict__ bv,
              unsigned short* __restrict__ Qh, unsigned short* __restrict__ Kh,
              unsigned short* __restrict__ VT) {
    const int K = D_;
    __shared__ __align__(16) unsigned short smem[2 * 8192];
    const int tid = threadIdx.x, lane = tid & 63, wid = tid >> 6;
    const int bid = blockIdx.x;
    const int row0 = (bid & 63) * 128;
    const int bx = bid >> 6;
    const int col0 = bx * 128;
    const int rh = (wid >> 1) * 64, ch = (wid & 1) * 64;
    const int fr = lane & 15, fq = lane >> 4;
    const int srow = wid * 32 + (lane >> 2);
    const int skoff = (lane & 3) * 8;
    const unsigned short* gA0 = A + (size_t)(row0 + srow) * K + skoff;
    const unsigned short* gA1 = gA0 + (size_t)16 * K;
    const unsigned short* gB0 = Bt + (size_t)(col0 + srow) * K + skoff;
    const unsigned short* gB1 = gB0 + (size_t)16 * K;

    f32x4 acc[4][4] = {};
    const int nk = K >> 5;   // 24
    {
        unsigned short* s = smem;
        __builtin_amdgcn_global_load_lds((ga_u32*)gA0, (lds_u32*)&s[wid * 1024], 16, 0, 0);
        __builtin_amdgcn_global_load_lds((ga_u32*)gA1, (lds_u32*)&s[wid * 1024 + 512], 16, 0, 0);
        __builtin_amdgcn_global_load_lds((ga_u32*)gB0, (lds_u32*)&s[4096 + wid * 1024], 16, 0, 0);
        __builtin_amdgcn_global_load_lds((ga_u32*)gB1, (lds_u32*)&s[4096 + wid * 1024 + 512], 16, 0, 0);
    }
    for (int kt = 0; kt < nk; ++kt) {
        __syncthreads();
        if (kt + 1 < nk) {
            int k0 = (kt + 1) << 5;
            unsigned short* s = smem + ((kt + 1) & 1) * 8192;
            __builtin_amdgcn_global_load_lds((ga_u32*)(gA0 + k0), (lds_u32*)&s[wid * 1024], 16, 0, 0);
            __builtin_amdgcn_global_load_lds((ga_u32*)(gA1 + k0), (lds_u32*)&s[wid * 1024 + 512], 16, 0, 0);
            __builtin_amdgcn_global_load_lds((ga_u32*)(gB0 + k0), (lds_u32*)&s[4096 + wid * 1024], 16, 0, 0);
            __builtin_amdgcn_global_load_lds((ga_u32*)(gB1 + k0), (lds_u32*)&s[4096 + wid * 1024 + 512], 16, 0, 0);
        }
        const unsigned short* sA = smem + (kt & 1) * 8192;
        const unsigned short* sB = sA + 4096;
        s16x8 af[4], bf[4];
#pragma unroll
        for (int i = 0; i < 4; ++i)
            af[i] = *(const s16x8*)&sA[(rh + 16 * i + fr) * 32 + fq * 8];
#pragma unroll
        for (int j = 0; j < 4; ++j)
            bf[j] = *(const s16x8*)&sB[(ch + 16 * j + fr) * 32 + fq * 8];
#pragma unroll
        for (int i = 0; i < 4; ++i)
#pragma unroll
            for (int j = 0; j < 4; ++j)
                acc[i][j] = __builtin_amdgcn_mfma_f32_16x16x32_bf16(af[i], bf[j], acc[i][j], 0, 0, 0);
    }
    const int seg = bx / 6;
    const int colbase = col0 - seg * D_;
    const float* bias = (seg == 0) ? bq : (seg == 1) ? bk : bv;
    if (seg == 2) {
#pragma unroll
        for (int j = 0; j < 4; ++j) {
            int col_l = colbase + ch + 16 * j + fr;
            float bb = bias[col_l];
#pragma unroll
            for (int i = 0; i < 4; ++i) {
                int rowbase = row0 + rh + 16 * i + fq * 4;
                ushort4 o;
                o.x = (unsigned short)bf16_rne(acc[i][j][0] + bb);
                o.y = (unsigned short)bf16_rne(acc[i][j][1] + bb);
                o.z = (unsigned short)bf16_rne(acc[i][j][2] + bb);
                o.w = (unsigned short)bf16_rne(acc[i][j][3] + bb);
                *(ushort4*)&VT[(size_t)col_l * ROWS_ + rowbase] = o;
            }
        }
    } else {
        unsigned short* dst = (seg == 0) ? Qh : Kh;
        unsigned short* sC = smem;
#pragma unroll
        for (int hh = 0; hh < 2; ++hh) {
            __syncthreads();
            if ((wid >> 1) == hh) {
#pragma unroll
                for (int j = 0; j < 4; ++j) {
                    float bb = bias[colbase + ch + 16 * j + fr];
#pragma unroll
                    for (int i = 0; i < 4; ++i)
#pragma unroll
                        for (int r = 0; r < 4; ++r)
                            sC[(16 * i + fq * 4 + r) * 136 + ch + 16 * j + fr] =
                                (unsigned short)bf16_rne(acc[i][j][r] + bb);
                }
            }
            __syncthreads();
#pragma unroll
            for (int p = 0; p < 4; ++p) {
                int seg2 = p * 256 + tid;
                int r = seg2 >> 4, c8 = (seg2 & 15) * 8;
                *(u16x8*)&dst[(size_t)(row0 + hh * 64 + r) * D_ + colbase + c8] =
                    *(const u16x8*)&sC[r * 136 + c8];
            }
        }
    }
}

// ---------------------------------------------------------------------------
// bf16 MFMA block-sparse attention (verified round 3, unchanged).
// ---------------------------------------------------------------------------
template <bool EDGE>
__global__ __launch_bounds__(256, 4)
void attn_mfma(const unsigned short* __restrict__ Qb, const unsigned short* __restrict__ Kb,
               const unsigned short* __restrict__ VTb, const int* __restrict__ rb,
               unsigned short* __restrict__ ctx, float* __restrict__ scratch) {
    __shared__ __align__(16) unsigned short sQ[64][72];
    __shared__ __align__(16) unsigned short sK[64][72];
    __shared__ __align__(16) unsigned short sVT[64][72];
    __shared__ __align__(16) unsigned short sP[4][16][72];
    __shared__ int sList[16];
    const int tid = threadIdx.x, lane = tid & 63, wid = tid >> 6;
    const int fr = lane & 15, fq = lane >> 4;
    int qb, h, b, nkb, slice = 0;
    if (EDGE) {
        int part = blockIdx.x & 3;
        int hh = (blockIdx.x >> 2) % H_;
        int be = (blockIdx.x >> 2) / H_;
        int eb = be & 1;
        b = be >> 1;
        h = hh;
        qb = eb ? (NB_ - 1) : 0;
        nkb = 16;
        slice = ((b * 2 + eb) * H_ + h) * 4 + part;
        if (tid < 16) sList[tid] = part * 16 + tid;
    } else {
        qb = blockIdx.x % (NB_ - 2) + 1;
        h = (blockIdx.x / (NB_ - 2)) % H_;
        b = blockIdx.x / ((NB_ - 2) * H_);
        nkb = 8;
        if (tid < 8) {
            int e;
            if (tid == 0) e = 0;
            else if (tid == 1) e = NB_ - 1;
            else if (tid < 5) e = qb + (tid - 3);
            else e = rb[(h * NB_ + qb) * 3 + (tid - 5)];
            sList[tid] = e;
        }
    }
    const int qrow0 = b * N_ + qb * 64;
    const unsigned short* Qg = Qb + (size_t)qrow0 * D_ + h * 64;
#pragma unroll
    for (int p = 0; p < 2; ++p) {
        int idx = p * 256 + tid;
        int r = idx >> 3, o = (idx & 7) * 8;
        *(u16x8*)&sQ[r][o] = *(const u16x8*)(Qg + (size_t)r * D_ + o);
    }
    f32x4 oacc[4] = {};
    float l_part[4] = {};
    __syncthreads();
    s16x8 aq0 = *(const s16x8*)&sQ[wid * 16 + fr][fq * 8];
    s16x8 aq1 = *(const s16x8*)&sQ[wid * 16 + fr][32 + fq * 8];

    for (int kb = 0; kb < nkb; ++kb) {
        const int kblk = sList[kb];
        const int keyrow0 = b * N_ + kblk * 64;
        __syncthreads();
        const unsigned short* Kg = Kb + (size_t)keyrow0 * D_ + h * 64;
#pragma unroll
        for (int p = 0; p < 2; ++p) {
            int idx = p * 256 + tid;
            int r = idx >> 3, o = (idx & 7) * 8;
            *(u16x8*)&sK[r][o] = *(const u16x8*)(Kg + (size_t)r * D_ + o);
        }
        const unsigned short* Vg = VTb + (size_t)(h * 64) * ROWS_ + keyrow0;
#pragma unroll
        for (int p = 0; p < 2; ++p) {
            int idx = p * 256 + tid;
            int d = idx >> 3, o = (idx & 7) * 8;
            *(u16x8*)&sVT[d][o] = *(const u16x8*)(Vg + (size_t)d * ROWS_ + o);
        }
        __syncthreads();
#pragma unroll
        for (int g = 0; g < 4; ++g) {
            s16x8 bk0 = *(const s16x8*)&sK[g * 16 + fr][fq * 8];
            s16x8 bk1 = *(const s16x8*)&sK[g * 16 + fr][32 + fq * 8];
            f32x4 s = {};
            s = __builtin_amdgcn_mfma_f32_16x16x32_bf16(aq0, bk0, s, 0, 0, 0);
            s = __builtin_amdgcn_mfma_f32_16x16x32_bf16(aq1, bk1, s, 0, 0, 0);
#pragma unroll
            for (int r = 0; r < 4; ++r) {
                float pv = __expf(s[r] * 0.125f);
                l_part[r] += pv;
                sP[wid][fq * 4 + r][g * 16 + fr] = (unsigned short)bf16_rne(pv);
            }
        }
        s16x8 ap0 = *(const s16x8*)&sP[wid][fr][fq * 8];
        s16x8 ap1 = *(const s16x8*)&sP[wid][fr][32 + fq * 8];
#pragma unroll
        for (int g = 0; g < 4; ++g) {
            s16x8 bv0 = *(const s16x8*)&sVT[g * 16 + fr][fq * 8];
            s16x8 bv1 = *(const s16x8*)&sVT[g * 16 + fr][32 + fq * 8];
            oacc[g] = __builtin_amdgcn_mfma_f32_16x16x32_bf16(ap0, bv0, oacc[g], 0, 0, 0);
            oacc[g] = __builtin_amdgcn_mfma_f32_16x16x32_bf16(ap1, bv1, oacc[g], 0, 0, 0);
        }
    }
    float l4[4];
#pragma unroll
    for (int r = 0; r < 4; ++r) {
        float lv = l_part[r];
        lv += __shfl_xor(lv, 1, 64);
        lv += __shfl_xor(lv, 2, 64);
        lv += __shfl_xor(lv, 4, 64);
        lv += __shfl_xor(lv, 8, 64);
        l4[r] = lv;
    }
    if (EDGE) {
        float* sc = scratch + (size_t)slice * (64 * 64 + 64);
#pragma unroll
        for (int g = 0; g < 4; ++g)
#pragma unroll
            for (int r = 0; r < 4; ++r)
                sc[(wid * 16 + fq * 4 + r) * 64 + g * 16 + fr] = oacc[g][r];
        if (fr == 0) {
#pragma unroll
            for (int r = 0; r < 4; ++r)
                sc[4096 + wid * 16 + fq * 4 + r] = l4[r];
        }
    } else {
        __syncthreads();
#pragma unroll
        for (int g = 0; g < 4; ++g) {
#pragma unroll
            for (int r = 0; r < 4; ++r) {
                float v = oacc[g][r] / l4[r];
                sK[wid * 16 + fq * 4 + r][g * 16 + fr] = (unsigned short)bf16_rne(v);
            }
        }
        __syncthreads();
        unsigned short* Cg = ctx + (size_t)qrow0 * D_ + h * 64;
#pragma unroll
        for (int p = 0; p < 2; ++p) {
            int idx = p * 256 + tid;
            int r = idx >> 3, o = (idx & 7) * 8;
            *(u16x8*)(Cg + (size_t)r * D_ + o) = *(const u16x8*)&sK[r][o];
        }
    }
}

__global__ __launch_bounds__(256)
void edge_combine(const float* __restrict__ scratch, unsigned short* __restrict__ ctx) {
    const int bid = blockIdx.x;
    const int h = bid % H_;
    const int eb = (bid / H_) & 1;
    const int b = bid / (2 * H_);
    const int qb = eb ? (NB_ - 1) : 0;
    const int qrow0 = b * N_ + qb * 64;
    const int slice0 = bid * 4;
    for (int e = threadIdx.x; e < 4096; e += 256) {
        int row = e >> 6, col = e & 63;
        float o = 0.f, l = 0.f;
#pragma unroll
        for (int p = 0; p < 4; ++p) {
            const float* sc = scratch + (size_t)(slice0 + p) * (64 * 64 + 64);
            o += sc[row * 64 + col];
            l += sc[4096 + row];
        }
        ctx[(size_t)(qrow0 + row) * D_ + h * 64 + col] = (unsigned short)bf16_rne(o / l);
    }
}

// ---------------------------------------------------------------------------
// LayerNorm — bf16 residual stream, fp32 math.
// ---------------------------------------------------------------------------
__global__ __launch_bounds__(256)
void embed_ln_kernel(const float* __restrict__ emb, const float* __restrict__ pos,
                     const float* __restrict__ tt, const float* __restrict__ g,
                     const float* __restrict__ bb, unsigned short* __restrict__ out) {
    __shared__ float red1[4], red2[4];
    const int row = blockIdx.x;
    const int n = row & (N_ - 1);
    const int t = threadIdx.x;
    float v[3];
#pragma unroll
    for (int i = 0; i < 3; ++i) {
        int d = t + i * 256;
        v[i] = emb[(size_t)row * D_ + d] + pos[(size_t)n * D_ + d] + tt[d];
    }
    float s = v[0] + v[1] + v[2];
#pragma unroll
    for (int off = 32; off > 0; off >>= 1) s += __shfl_xor(s, off, 64);
    if ((t & 63) == 0) red1[t >> 6] = s;
    __syncthreads();
    float mu = (red1[0] + red1[1] + red1[2] + red1[3]) * (1.0f / D_);
    float q = 0;
#pragma unroll
    for (int i = 0; i < 3; ++i) { float dv = v[i] - mu; q += dv * dv; }
#pragma unroll
    for (int off = 32; off > 0; off >>= 1) q += __shfl_xor(q, off, 64);
    if ((t & 63) == 0) red2[t >> 6] = q;
    __syncthreads();
    float var = (red2[0] + red2[1] + red2[2] + red2[3]) * (1.0f / D_);
    float rs = rsqrtf(var + 1e-12f);
#pragma unroll
    for (int i = 0; i < 3; ++i) {
        int d = t + i * 256;
        out[(size_t)row * D_ + d] = (unsigned short)bf16_rne((v[i] - mu) * rs * g[d] + bb[d]);
    }
}

__global__ __launch_bounds__(256)
void add_ln_kernel(const unsigned short* __restrict__ X, const float* __restrict__ Y,
                   const float* __restrict__ g, const float* __restrict__ bb,
                   unsigned short* __restrict__ out) {
    __shared__ float red1[4], red2[4];
    const int row = blockIdx.x;
    const int t = threadIdx.x;
    float v[3];
#pragma unroll
    for (int i = 0; i < 3; ++i) {
        int d = t + i * 256;
        v[i] = bfh2f(X[(size_t)row * D_ + d]) + Y[(size_t)row * D_ + d];
    }
    float s = v[0] + v[1] + v[2];
#pragma unroll
    for (int off = 32; off > 0; off >>= 1) s += __shfl_xor(s, off, 64);
    if ((t & 63) == 0) red1[t >> 6] = s;
    __syncthreads();
    float mu = (red1[0] + red1[1] + red1[2] + red1[3]) * (1.0f / D_);
    float q = 0;
#pragma unroll
    for (int i = 0; i < 3; ++i) { float dv = v[i] - mu; q += dv * dv; }
#pragma unroll
    for (int off = 32; off > 0; off >>= 1) q += __shfl_xor(q, off, 64);
    if ((t & 63) == 0) red2[t >> 6] = q;
    __syncthreads();
    float var = (red2[0] + red2[1] + red2[2] + red2[3]) * (1.0f / D_);
    float rs = rsqrtf(var + 1e-12f);
#pragma unroll
    for (int i = 0; i < 3; ++i) {
        int d = t + i * 256;
        out[(size_t)row * D_ + d] = (unsigned short)bf16_rne((v[i] - mu) * rs * g[d] + bb[d]);
    }
}

// ---------------------------------------------------------------------------
// Mean-pool over N then fc
// ---------------------------------------------------------------------------
__global__ __launch_bounds__(256)
void pool_partial_kernel(const unsigned short* __restrict__ X, float* __restrict__ partial) {
    int blk = blockIdx.x;
    int b = blk >> 4, c = blk & 15;
    int t = threadIdx.x;
#pragma unroll
    for (int i = 0; i < 3; ++i) {
        int d = t + i * 256;
        float s = 0.f;
        for (int n = 0; n < 256; ++n)
            s += bfh2f(X[((size_t)(b * N_ + c * 256 + n)) * D_ + d]);
        partial[(size_t)(b * 16 + c) * D_ + d] = s;
    }
}

__global__ __launch_bounds__(256)
void pool_final_kernel(const float* __restrict__ partial, const float* __restrict__ fcw,
                       const float* __restrict__ fcb, float* __restrict__ out) {
    __shared__ float red[4];
    int t = threadIdx.x;
    for (int b = 0; b < B_; ++b) {
        float s = 0.f;
#pragma unroll
        for (int i = 0; i < 3; ++i) {
            int d = t + i * 256;
            float ps = 0.f;
#pragma unroll
            for (int c = 0; c < 16; ++c) ps += partial[(size_t)(b * 16 + c) * D_ + d];
            s += ps * (1.0f / N_) * fcw[d];
        }
#pragma unroll
        for (int off = 32; off > 0; off >>= 1) s += __shfl_xor(s, off, 64);
        __syncthreads();
        if ((t & 63) == 0) red[t >> 6] = s;
        __syncthreads();
        if (t == 0) out[b] = red[0] + red[1] + red[2] + red[3] + fcb[0];
    }
}

// ---------------------------------------------------------------------------
extern "C" void kernel_launch(void* const* d_in, const int* in_sizes, int n_in,
                              void* d_out, int out_size, void* d_ws, size_t ws_size,
                              hipStream_t stream) {
    (void)in_sizes; (void)n_in; (void)out_size; (void)ws_size;
    const float* emb  = (const float*)d_in[0];
    const int*   rblk = (const int*)d_in[1];
    const float* pos  = (const float*)d_in[2];
    const float* tt   = (const float*)d_in[3];
    const float* elg  = (const float*)d_in[4];
    const float* elb  = (const float*)d_in[5];
    const float* Wq   = (const float*)d_in[6];
    const float* bq   = (const float*)d_in[7];
    const float* Wk   = (const float*)d_in[8];
    const float* bk   = (const float*)d_in[9];
    const float* Wv   = (const float*)d_in[10];
    const float* bv   = (const float*)d_in[11];
    const float* Wo   = (const float*)d_in[12];
    const float* bo   = (const float*)d_in[13];
    const float* ln1g = (const float*)d_in[14];
    const float* ln1b = (const float*)d_in[15];
    const float* Wi   = (const float*)d_in[16];
    const float* bi   = (const float*)d_in[17];
    const float* Wd   = (const float*)d_in[18];
    const float* bd   = (const float*)d_in[19];
    const float* ln2g = (const float*)d_in[20];
    const float* ln2b = (const float*)d_in[21];
    const float* fcw  = (const float*)d_in[22];
    const float* fcb  = (const float*)d_in[23];
    float* outp = (float*)d_out;

    const size_t R = (size_t)ROWS_ * D_;          // 6,291,456
    float* base = (float*)d_ws;
    unsigned short* Xh  = (unsigned short*)base;
    unsigned short* Abh = (unsigned short*)(base + R / 2);
    float* G32 = base + R;
    unsigned short* Qh  = (unsigned short*)(base + 2 * R);
    unsigned short* Kh  = (unsigned short*)(base + 2 * R + R / 2);
    unsigned short* VTh = (unsigned short*)(base + 3 * R);
    unsigned short* Ch  = (unsigned short*)(base + 3 * R + R / 2);
    unsigned short* Hh  = (unsigned short*)(base + 2 * R);    // FFN hidden overlays QKVC
    unsigned short* Wt  = (unsigned short*)(base + 4 * R);
    float* Esc = base + 4 * R + 7077888;
    float* Pp  = Esc + 798720;

    const size_t LW = 7077888;
    const int rows = ROWS_;
    dim3 blk(256);

    prep_weights<<<2 * 1728, blk, 0, stream>>>(Wq, Wk, Wv, Wo, Wi, Wd, Wt);

    embed_ln_kernel<<<rows, blk, 0, stream>>>(emb, pos, tt, elg, elb, Xh);

    for (int l = 0; l < LAYERS_; ++l) {
        const float* bq_l = bq + (size_t)l * D_;
        const float* bk_l = bk + (size_t)l * D_;
        const float* bv_l = bv + (size_t)l * D_;
        const float* bo_l = bo + (size_t)l * D_;
        const float* bi_l = bi + (size_t)l * FF_;
        const float* bd_l = bd + (size_t)l * D_;
        const float* l1g = ln1g + (size_t)l * D_;
        const float* l1b = ln1b + (size_t)l * D_;
        const float* l2g = ln2g + (size_t)l * D_;
        const float* l2b = ln2b + (size_t)l * D_;
        const int* rb_l = rblk + (size_t)l * H_ * NB_ * 3;
        unsigned short* QKVt = Wt + l * LW;
        unsigned short* Ot = QKVt + 2304 * 768;
        unsigned short* It = Ot + 768 * 768;
        unsigned short* Dt = It + 3072 * 768;

        gemm_qkv<<<18 * 64, blk, 0, stream>>>(Xh, QKVt, bq_l, bk_l, bv_l, Qh, Kh, VTh);

        attn_mfma<false><<<B_ * H_ * (NB_ - 2), blk, 0, stream>>>(Qh, Kh, VTh, rb_l, Ch, Esc);
        attn_mfma<true><<<B_ * 2 * H_ * 4, blk, 0, stream>>>(Qh, Kh, VTh, rb_l, Ch, Esc);
        edge_combine<<<B_ * 2 * H_, blk, 0, stream>>>(Esc, Ch);

        gemm_bt<0><<<6 * 64, blk, 0, stream>>>(Ch, Ot, bo_l, G32, D_, D_, 0);
        add_ln_kernel<<<rows, blk, 0, stream>>>(Xh, G32, l1g, l1b, Abh);

        gemm_bt<1><<<24 * 64, blk, 0, stream>>>(Abh, It, bi_l, Hh, FF_, D_, 1);
        gemm_bt<0><<<6 * 64, blk, 0, stream>>>(Hh, Dt, bd_l, G32, D_, FF_, 0);

        add_ln_kernel<<<rows, blk, 0, stream>>>(Abh, G32, l2g, l2b, Xh);
    }

    pool_partial_kernel<<<B_ * 16, blk, 0, stream>>>(Xh, Pp);
    pool_final_kernel<<<1, blk, 0, stream>>>(Pp, fcw, fcb, outp);
}

// Round 8
// 747.741 us; speedup vs baseline: 1.2960x; 1.0087x over previous
//
#include <hip/hip_runtime.h>
#include <math.h>

#define B_ 2
#define N_ 4096
#define D_ 768
#define H_ 12
#define DH_ 64
#define NB_ 64
#define FF_ 3072
#define LAYERS_ 2
#define ROWS_ (B_ * N_)   // 8192

typedef __attribute__((ext_vector_type(8))) short s16x8;            // bf16x8 frag
typedef __attribute__((ext_vector_type(8))) unsigned short u16x8;   // staging
typedef __attribute__((ext_vector_type(4))) float f32x4;

typedef const __attribute__((address_space(1))) unsigned int ga_u32;
typedef __attribute__((address_space(3))) unsigned int lds_u32;

static __device__ __forceinline__ float gelu_fast(float x) {
    float z2 = 1.5957691216057308f * x * (1.0f + 0.044715f * x * x);
    return x * __builtin_amdgcn_rcpf(1.0f + __expf(-z2));
}

static __device__ __forceinline__ unsigned bf16_rne(float f) {
    unsigned u = __float_as_uint(f);
    return (u + 0x7FFFu + ((u >> 16) & 1u)) >> 16;
}
static __device__ __forceinline__ float bfh2f(unsigned short h) {
    return __uint_as_float(((unsigned)h) << 16);
}

// ---------------------------------------------------------------------------
// Weight prep, all transposes in ONE launch (unchanged).
// ---------------------------------------------------------------------------
__global__ __launch_bounds__(256)
void prep_weights(const float* __restrict__ Wq, const float* __restrict__ Wk,
                  const float* __restrict__ Wv, const float* __restrict__ Wo,
                  const float* __restrict__ Wi, const float* __restrict__ Wd,
                  unsigned short* __restrict__ Wt) {
    const size_t LW = 7077888;
    int bid = blockIdx.x;
    int l = bid / 1728, r = bid % 1728;
    const float* W; unsigned short* T; int K, N, t, nx;
    if (r < 576) {
        int which = r / 144; t = r % 144; nx = 12; K = 768; N = 768;
        W = (which == 0 ? Wq : which == 1 ? Wk : which == 2 ? Wv : Wo) + (size_t)l * D_ * D_;
        T = Wt + l * LW + (size_t)(which < 3 ? which * 768 * 768 : 2304 * 768);
    } else if (r < 1152) {
        t = r - 576; nx = 48; K = 768; N = 3072;
        W = Wi + (size_t)l * D_ * FF_;
        T = Wt + l * LW + (size_t)(2304 * 768 + 768 * 768);
    } else {
        t = r - 1152; nx = 12; K = 3072; N = 768;
        W = Wd + (size_t)l * FF_ * D_;
        T = Wt + l * LW + (size_t)(2304 * 768 + 768 * 768 + 3072 * 768);
    }
    const int bx = t % nx, by = t / nx;
    __shared__ unsigned short tile[64][72];
    const int k0 = by * 64, n0 = bx * 64;
    const int tt = threadIdx.x;
    const int rr = tt >> 2, c0 = (tt & 3) * 16;
    const float* src = W + (size_t)(k0 + rr) * N + n0 + c0;
#pragma unroll
    for (int j = 0; j < 4; ++j) {
        float4 v = *(const float4*)(src + j * 4);
        tile[rr][c0 + j * 4 + 0] = (unsigned short)bf16_rne(v.x);
        tile[rr][c0 + j * 4 + 1] = (unsigned short)bf16_rne(v.y);
        tile[rr][c0 + j * 4 + 2] = (unsigned short)bf16_rne(v.z);
        tile[rr][c0 + j * 4 + 3] = (unsigned short)bf16_rne(v.w);
    }
    __syncthreads();
    const int nr = tt >> 2, kc = (tt & 3) * 16;
    unsigned short* dst = T + (size_t)(n0 + nr) * K + k0 + kc;
    ushort4 o;
#pragma unroll
    for (int j = 0; j < 4; ++j) {
        o.x = tile[kc + j * 4 + 0][nr];
        o.y = tile[kc + j * 4 + 1][nr];
        o.z = tile[kc + j * 4 + 2][nr];
        o.w = tile[kc + j * 4 + 3][nr];
        *(ushort4*)(dst + j * 4) = o;
    }
}

// ---------------------------------------------------------------------------
// bf16 GEMM core, BK=32, double-buffered, XCD-swizzled (round-7 verified).
// OMODE: 0 = fp32 direct stores, 1 = bf16 via LDS-roundtrip coalesced stores.
// ---------------------------------------------------------------------------
template <int OMODE>
__global__ __launch_bounds__(256)
void gemm_bt(const unsigned short* __restrict__ A, const unsigned short* __restrict__ Bt,
             const float* __restrict__ bias, void* __restrict__ Cv,
             int N, int K, int gelu) {
    __shared__ __align__(16) unsigned short smem[2 * 8192];
    const int tid = threadIdx.x, lane = tid & 63, wid = tid >> 6;
    const int bid = blockIdx.x;
    const int row0 = (bid & 63) * 128, col0 = (bid >> 6) * 128;
    const int rh = (wid >> 1) * 64, ch = (wid & 1) * 64;
    const int fr = lane & 15, fq = lane >> 4;
    const int srow = wid * 32 + (lane >> 2);
    const int skoff = (lane & 3) * 8;
    const unsigned short* gA0 = A + (size_t)(row0 + srow) * K + skoff;
    const unsigned short* gA1 = gA0 + (size_t)16 * K;
    const unsigned short* gB0 = Bt + (size_t)(col0 + srow) * K + skoff;
    const unsigned short* gB1 = gB0 + (size_t)16 * K;

    f32x4 acc[4][4] = {};
    const int nk = K >> 5;
    {
        unsigned short* s = smem;
        __builtin_amdgcn_global_load_lds((ga_u32*)gA0, (lds_u32*)&s[wid * 1024], 16, 0, 0);
        __builtin_amdgcn_global_load_lds((ga_u32*)gA1, (lds_u32*)&s[wid * 1024 + 512], 16, 0, 0);
        __builtin_amdgcn_global_load_lds((ga_u32*)gB0, (lds_u32*)&s[4096 + wid * 1024], 16, 0, 0);
        __builtin_amdgcn_global_load_lds((ga_u32*)gB1, (lds_u32*)&s[4096 + wid * 1024 + 512], 16, 0, 0);
    }
    for (int kt = 0; kt < nk; ++kt) {
        __syncthreads();
        if (kt + 1 < nk) {
            int k0 = (kt + 1) << 5;
            unsigned short* s = smem + ((kt + 1) & 1) * 8192;
            __builtin_amdgcn_global_load_lds((ga_u32*)(gA0 + k0), (lds_u32*)&s[wid * 1024], 16, 0, 0);
            __builtin_amdgcn_global_load_lds((ga_u32*)(gA1 + k0), (lds_u32*)&s[wid * 1024 + 512], 16, 0, 0);
            __builtin_amdgcn_global_load_lds((ga_u32*)(gB0 + k0), (lds_u32*)&s[4096 + wid * 1024], 16, 0, 0);
            __builtin_amdgcn_global_load_lds((ga_u32*)(gB1 + k0), (lds_u32*)&s[4096 + wid * 1024 + 512], 16, 0, 0);
        }
        const unsigned short* sA = smem + (kt & 1) * 8192;
        const unsigned short* sB = sA + 4096;
        s16x8 af[4], bf[4];
#pragma unroll
        for (int i = 0; i < 4; ++i)
            af[i] = *(const s16x8*)&sA[(rh + 16 * i + fr) * 32 + fq * 8];
#pragma unroll
        for (int j = 0; j < 4; ++j)
            bf[j] = *(const s16x8*)&sB[(ch + 16 * j + fr) * 32 + fq * 8];
#pragma unroll
        for (int i = 0; i < 4; ++i)
#pragma unroll
            for (int j = 0; j < 4; ++j)
                acc[i][j] = __builtin_amdgcn_mfma_f32_16x16x32_bf16(af[i], bf[j], acc[i][j], 0, 0, 0);
    }
    if (OMODE == 0) {
#pragma unroll
        for (int j = 0; j < 4; ++j) {
            int col = col0 + ch + 16 * j + fr;
            float bb = bias[col];
#pragma unroll
            for (int i = 0; i < 4; ++i)
#pragma unroll
                for (int r = 0; r < 4; ++r) {
                    int row = row0 + rh + 16 * i + fq * 4 + r;
                    float v = acc[i][j][r] + bb;
                    if (gelu) v = gelu_fast(v);
                    ((float*)Cv)[(size_t)row * N + col] = v;
                }
        }
    } else {
        unsigned short* sC = smem;
#pragma unroll
        for (int hh = 0; hh < 2; ++hh) {
            __syncthreads();
            if ((wid >> 1) == hh) {
#pragma unroll
                for (int j = 0; j < 4; ++j) {
                    float bb = bias[col0 + ch + 16 * j + fr];
#pragma unroll
                    for (int i = 0; i < 4; ++i)
#pragma unroll
                        for (int r = 0; r < 4; ++r) {
                            float v = acc[i][j][r] + bb;
                            if (gelu) v = gelu_fast(v);
                            sC[(16 * i + fq * 4 + r) * 136 + ch + 16 * j + fr] =
                                (unsigned short)bf16_rne(v);
                        }
                }
            }
            __syncthreads();
#pragma unroll
            for (int p = 0; p < 4; ++p) {
                int seg = p * 256 + tid;
                int r = seg >> 4, c8 = (seg & 15) * 8;
                *(u16x8*)&((unsigned short*)Cv)[(size_t)(row0 + hh * 64 + r) * N + col0 + c8] =
                    *(const u16x8*)&sC[r * 136 + c8];
            }
        }
    }
}

// Fused QKV GEMM (unchanged from round 7).
__global__ __launch_bounds__(256)
void gemm_qkv(const unsigned short* __restrict__ A, const unsigned short* __restrict__ Bt,
              const float* __restrict__ bq, const float* __restrict__ bk,
              const float* __restrict__ bv,
              unsigned short* __restrict__ Qh, unsigned short* __restrict__ Kh,
              unsigned short* __restrict__ VT) {
    const int K = D_;
    __shared__ __align__(16) unsigned short smem[2 * 8192];
    const int tid = threadIdx.x, lane = tid & 63, wid = tid >> 6;
    const int bid = blockIdx.x;
    const int row0 = (bid & 63) * 128;
    const int bx = bid >> 6;
    const int col0 = bx * 128;
    const int rh = (wid >> 1) * 64, ch = (wid & 1) * 64;
    const int fr = lane & 15, fq = lane >> 4;
    const int srow = wid * 32 + (lane >> 2);
    const int skoff = (lane & 3) * 8;
    const unsigned short* gA0 = A + (size_t)(row0 + srow) * K + skoff;
    const unsigned short* gA1 = gA0 + (size_t)16 * K;
    const unsigned short* gB0 = Bt + (size_t)(col0 + srow) * K + skoff;
    const unsigned short* gB1 = gB0 + (size_t)16 * K;

    f32x4 acc[4][4] = {};
    const int nk = K >> 5;
    {
        unsigned short* s = smem;
        __builtin_amdgcn_global_load_lds((ga_u32*)gA0, (lds_u32*)&s[wid * 1024], 16, 0, 0);
        __builtin_amdgcn_global_load_lds((ga_u32*)gA1, (lds_u32*)&s[wid * 1024 + 512], 16, 0, 0);
        __builtin_amdgcn_global_load_lds((ga_u32*)gB0, (lds_u32*)&s[4096 + wid * 1024], 16, 0, 0);
        __builtin_amdgcn_global_load_lds((ga_u32*)gB1, (lds_u32*)&s[4096 + wid * 1024 + 512], 16, 0, 0);
    }
    for (int kt = 0; kt < nk; ++kt) {
        __syncthreads();
        if (kt + 1 < nk) {
            int k0 = (kt + 1) << 5;
            unsigned short* s = smem + ((kt + 1) & 1) * 8192;
            __builtin_amdgcn_global_load_lds((ga_u32*)(gA0 + k0), (lds_u32*)&s[wid * 1024], 16, 0, 0);
            __builtin_amdgcn_global_load_lds((ga_u32*)(gA1 + k0), (lds_u32*)&s[wid * 1024 + 512], 16, 0, 0);
            __builtin_amdgcn_global_load_lds((ga_u32*)(gB0 + k0), (lds_u32*)&s[4096 + wid * 1024], 16, 0, 0);
            __builtin_amdgcn_global_load_lds((ga_u32*)(gB1 + k0), (lds_u32*)&s[4096 + wid * 1024 + 512], 16, 0, 0);
        }
        const unsigned short* sA = smem + (kt & 1) * 8192;
        const unsigned short* sB = sA + 4096;
        s16x8 af[4], bf[4];
#pragma unroll
        for (int i = 0; i < 4; ++i)
            af[i] = *(const s16x8*)&sA[(rh + 16 * i + fr) * 32 + fq * 8];
#pragma unroll
        for (int j = 0; j < 4; ++j)
            bf[j] = *(const s16x8*)&sB[(ch + 16 * j + fr) * 32 + fq * 8];
#pragma unroll
        for (int i = 0; i < 4; ++i)
#pragma unroll
            for (int j = 0; j < 4; ++j)
                acc[i][j] = __builtin_amdgcn_mfma_f32_16x16x32_bf16(af[i], bf[j], acc[i][j], 0, 0, 0);
    }
    const int seg = bx / 6;
    const int colbase = col0 - seg * D_;
    const float* bias = (seg == 0) ? bq : (seg == 1) ? bk : bv;
    if (seg == 2) {
#pragma unroll
        for (int j = 0; j < 4; ++j) {
            int col_l = colbase + ch + 16 * j + fr;
            float bb = bias[col_l];
#pragma unroll
            for (int i = 0; i < 4; ++i) {
                int rowbase = row0 + rh + 16 * i + fq * 4;
                ushort4 o;
                o.x = (unsigned short)bf16_rne(acc[i][j][0] + bb);
                o.y = (unsigned short)bf16_rne(acc[i][j][1] + bb);
                o.z = (unsigned short)bf16_rne(acc[i][j][2] + bb);
                o.w = (unsigned short)bf16_rne(acc[i][j][3] + bb);
                *(ushort4*)&VT[(size_t)col_l * ROWS_ + rowbase] = o;
            }
        }
    } else {
        unsigned short* dst = (seg == 0) ? Qh : Kh;
        unsigned short* sC = smem;
#pragma unroll
        for (int hh = 0; hh < 2; ++hh) {
            __syncthreads();
            if ((wid >> 1) == hh) {
#pragma unroll
                for (int j = 0; j < 4; ++j) {
                    float bb = bias[colbase + ch + 16 * j + fr];
#pragma unroll
                    for (int i = 0; i < 4; ++i)
#pragma unroll
                        for (int r = 0; r < 4; ++r)
                            sC[(16 * i + fq * 4 + r) * 136 + ch + 16 * j + fr] =
                                (unsigned short)bf16_rne(acc[i][j][r] + bb);
                }
            }
            __syncthreads();
#pragma unroll
            for (int p = 0; p < 4; ++p) {
                int seg2 = p * 256 + tid;
                int r = seg2 >> 4, c8 = (seg2 & 15) * 8;
                *(u16x8*)&dst[(size_t)(row0 + hh * 64 + r) * D_ + colbase + c8] =
                    *(const u16x8*)&sC[r * 136 + c8];
            }
        }
    }
}

// ---------------------------------------------------------------------------
// bf16 MFMA block-sparse attention with REGISTER-PREFETCHED K/V staging:
// kb+1's global loads are issued right after the staging barrier, flying
// during the whole QK/exp/PV phase (same one-barrier-gap trick as gemm_bt).
// ---------------------------------------------------------------------------
template <bool EDGE>
__global__ __launch_bounds__(256, 4)
void attn_mfma(const unsigned short* __restrict__ Qb, const unsigned short* __restrict__ Kb,
               const unsigned short* __restrict__ VTb, const int* __restrict__ rb,
               unsigned short* __restrict__ ctx, float* __restrict__ scratch) {
    __shared__ __align__(16) unsigned short sQ[64][72];
    __shared__ __align__(16) unsigned short sK[64][72];
    __shared__ __align__(16) unsigned short sVT[64][72];
    __shared__ __align__(16) unsigned short sP[4][16][72];
    __shared__ int sList[16];
    const int tid = threadIdx.x, lane = tid & 63, wid = tid >> 6;
    const int fr = lane & 15, fq = lane >> 4;
    int qb, h, b, nkb, slice = 0;
    if (EDGE) {
        int part = blockIdx.x & 3;
        int hh = (blockIdx.x >> 2) % H_;
        int be = (blockIdx.x >> 2) / H_;
        int eb = be & 1;
        b = be >> 1;
        h = hh;
        qb = eb ? (NB_ - 1) : 0;
        nkb = 16;
        slice = ((b * 2 + eb) * H_ + h) * 4 + part;
        if (tid < 16) sList[tid] = part * 16 + tid;
    } else {
        qb = blockIdx.x % (NB_ - 2) + 1;
        h = (blockIdx.x / (NB_ - 2)) % H_;
        b = blockIdx.x / ((NB_ - 2) * H_);
        nkb = 8;
        if (tid < 8) {
            int e;
            if (tid == 0) e = 0;
            else if (tid == 1) e = NB_ - 1;
            else if (tid < 5) e = qb + (tid - 3);
            else e = rb[(h * NB_ + qb) * 3 + (tid - 5)];
            sList[tid] = e;
        }
    }
    const int qrow0 = b * N_ + qb * 64;
    const unsigned short* Qg = Qb + (size_t)qrow0 * D_ + h * 64;
#pragma unroll
    for (int p = 0; p < 2; ++p) {
        int idx = p * 256 + tid;
        int r = idx >> 3, o = (idx & 7) * 8;
        *(u16x8*)&sQ[r][o] = *(const u16x8*)(Qg + (size_t)r * D_ + o);
    }
    f32x4 oacc[4] = {};
    float l_part[4] = {};
    __syncthreads();          // sQ + sList visible
    s16x8 aq0 = *(const s16x8*)&sQ[wid * 16 + fr][fq * 8];
    s16x8 aq1 = *(const s16x8*)&sQ[wid * 16 + fr][32 + fq * 8];

    // staging map (shared by K and V^T): r = row (K) or d (V^T), o = 8-col
    const int stg_r = tid >> 3, stg_o = (tid & 7) * 8;
    u16x8 kreg[2], vreg[2];
    {   // prefetch kb = 0
        int keyrow0 = b * N_ + sList[0] * 64;
        const unsigned short* Kg = Kb + (size_t)keyrow0 * D_ + h * 64;
        const unsigned short* Vg = VTb + (size_t)(h * 64) * ROWS_ + keyrow0;
#pragma unroll
        for (int p = 0; p < 2; ++p) {
            int r = stg_r + p * 32;
            kreg[p] = *(const u16x8*)(Kg + (size_t)r * D_ + stg_o);
            vreg[p] = *(const u16x8*)(Vg + (size_t)r * ROWS_ + stg_o);
        }
    }

    for (int kb = 0; kb < nkb; ++kb) {
        __syncthreads();      // prior iteration's sK/sVT reads done
#pragma unroll
        for (int p = 0; p < 2; ++p) {
            int r = stg_r + p * 32;
            *(u16x8*)&sK[r][stg_o] = kreg[p];
            *(u16x8*)&sVT[r][stg_o] = vreg[p];
        }
        __syncthreads();      // staged tile visible
        if (kb + 1 < nkb) {   // prefetch kb+1 — lands during compute below
            int keyrow0 = b * N_ + sList[kb + 1] * 64;
            const unsigned short* Kg = Kb + (size_t)keyrow0 * D_ + h * 64;
            const unsigned short* Vg = VTb + (size_t)(h * 64) * ROWS_ + keyrow0;
#pragma unroll
            for (int p = 0; p < 2; ++p) {
                int r = stg_r + p * 32;
                kreg[p] = *(const u16x8*)(Kg + (size_t)r * D_ + stg_o);
                vreg[p] = *(const u16x8*)(Vg + (size_t)r * ROWS_ + stg_o);
            }
        }
#pragma unroll
        for (int g = 0; g < 4; ++g) {
            s16x8 bk0 = *(const s16x8*)&sK[g * 16 + fr][fq * 8];
            s16x8 bk1 = *(const s16x8*)&sK[g * 16 + fr][32 + fq * 8];
            f32x4 s = {};
            s = __builtin_amdgcn_mfma_f32_16x16x32_bf16(aq0, bk0, s, 0, 0, 0);
            s = __builtin_amdgcn_mfma_f32_16x16x32_bf16(aq1, bk1, s, 0, 0, 0);
#pragma unroll
            for (int r = 0; r < 4; ++r) {
                float pv = __expf(s[r] * 0.125f);
                l_part[r] += pv;
                sP[wid][fq * 4 + r][g * 16 + fr] = (unsigned short)bf16_rne(pv);
            }
        }
        s16x8 ap0 = *(const s16x8*)&sP[wid][fr][fq * 8];
        s16x8 ap1 = *(const s16x8*)&sP[wid][fr][32 + fq * 8];
#pragma unroll
        for (int g = 0; g < 4; ++g) {
            s16x8 bv0 = *(const s16x8*)&sVT[g * 16 + fr][fq * 8];
            s16x8 bv1 = *(const s16x8*)&sVT[g * 16 + fr][32 + fq * 8];
            oacc[g] = __builtin_amdgcn_mfma_f32_16x16x32_bf16(ap0, bv0, oacc[g], 0, 0, 0);
            oacc[g] = __builtin_amdgcn_mfma_f32_16x16x32_bf16(ap1, bv1, oacc[g], 0, 0, 0);
        }
    }
    float l4[4];
#pragma unroll
    for (int r = 0; r < 4; ++r) {
        float lv = l_part[r];
        lv += __shfl_xor(lv, 1, 64);
        lv += __shfl_xor(lv, 2, 64);
        lv += __shfl_xor(lv, 4, 64);
        lv += __shfl_xor(lv, 8, 64);
        l4[r] = lv;
    }
    if (EDGE) {
        float* sc = scratch + (size_t)slice * (64 * 64 + 64);
#pragma unroll
        for (int g = 0; g < 4; ++g)
#pragma unroll
            for (int r = 0; r < 4; ++r)
                sc[(wid * 16 + fq * 4 + r) * 64 + g * 16 + fr] = oacc[g][r];
        if (fr == 0) {
#pragma unroll
            for (int r = 0; r < 4; ++r)
                sc[4096 + wid * 16 + fq * 4 + r] = l4[r];
        }
    } else {
        __syncthreads();
#pragma unroll
        for (int g = 0; g < 4; ++g) {
#pragma unroll
            for (int r = 0; r < 4; ++r) {
                float v = oacc[g][r] / l4[r];
                sK[wid * 16 + fq * 4 + r][g * 16 + fr] = (unsigned short)bf16_rne(v);
            }
        }
        __syncthreads();
        unsigned short* Cg = ctx + (size_t)qrow0 * D_ + h * 64;
#pragma unroll
        for (int p = 0; p < 2; ++p) {
            int idx = p * 256 + tid;
            int r = idx >> 3, o = (idx & 7) * 8;
            *(u16x8*)(Cg + (size_t)r * D_ + o) = *(const u16x8*)&sK[r][o];
        }
    }
}

__global__ __launch_bounds__(256)
void edge_combine(const float* __restrict__ scratch, unsigned short* __restrict__ ctx) {
    const int bid = blockIdx.x;
    const int h = bid % H_;
    const int eb = (bid / H_) & 1;
    const int b = bid / (2 * H_);
    const int qb = eb ? (NB_ - 1) : 0;
    const int qrow0 = b * N_ + qb * 64;
    const int slice0 = bid * 4;
    for (int e = threadIdx.x; e < 4096; e += 256) {
        int row = e >> 6, col = e & 63;
        float o = 0.f, l = 0.f;
#pragma unroll
        for (int p = 0; p < 4; ++p) {
            const float* sc = scratch + (size_t)(slice0 + p) * (64 * 64 + 64);
            o += sc[row * 64 + col];
            l += sc[4096 + row];
        }
        ctx[(size_t)(qrow0 + row) * D_ + h * 64 + col] = (unsigned short)bf16_rne(o / l);
    }
}

// ---------------------------------------------------------------------------
// LayerNorm — bf16 residual stream AND bf16 Y (GEMM outputs now bf16).
// ---------------------------------------------------------------------------
__global__ __launch_bounds__(256)
void embed_ln_kernel(const float* __restrict__ emb, const float* __restrict__ pos,
                     const float* __restrict__ tt, const float* __restrict__ g,
                     const float* __restrict__ bb, unsigned short* __restrict__ out) {
    __shared__ float red1[4], red2[4];
    const int row = blockIdx.x;
    const int n = row & (N_ - 1);
    const int t = threadIdx.x;
    float v[3];
#pragma unroll
    for (int i = 0; i < 3; ++i) {
        int d = t + i * 256;
        v[i] = emb[(size_t)row * D_ + d] + pos[(size_t)n * D_ + d] + tt[d];
    }
    float s = v[0] + v[1] + v[2];
#pragma unroll
    for (int off = 32; off > 0; off >>= 1) s += __shfl_xor(s, off, 64);
    if ((t & 63) == 0) red1[t >> 6] = s;
    __syncthreads();
    float mu = (red1[0] + red1[1] + red1[2] + red1[3]) * (1.0f / D_);
    float q = 0;
#pragma unroll
    for (int i = 0; i < 3; ++i) { float dv = v[i] - mu; q += dv * dv; }
#pragma unroll
    for (int off = 32; off > 0; off >>= 1) q += __shfl_xor(q, off, 64);
    if ((t & 63) == 0) red2[t >> 6] = q;
    __syncthreads();
    float var = (red2[0] + red2[1] + red2[2] + red2[3]) * (1.0f / D_);
    float rs = rsqrtf(var + 1e-12f);
#pragma unroll
    for (int i = 0; i < 3; ++i) {
        int d = t + i * 256;
        out[(size_t)row * D_ + d] = (unsigned short)bf16_rne((v[i] - mu) * rs * g[d] + bb[d]);
    }
}

__global__ __launch_bounds__(256)
void add_ln_kernel(const unsigned short* __restrict__ X, const unsigned short* __restrict__ Y,
                   const float* __restrict__ g, const float* __restrict__ bb,
                   unsigned short* __restrict__ out) {
    __shared__ float red1[4], red2[4];
    const int row = blockIdx.x;
    const int t = threadIdx.x;
    float v[3];
#pragma unroll
    for (int i = 0; i < 3; ++i) {
        int d = t + i * 256;
        v[i] = bfh2f(X[(size_t)row * D_ + d]) + bfh2f(Y[(size_t)row * D_ + d]);
    }
    float s = v[0] + v[1] + v[2];
#pragma unroll
    for (int off = 32; off > 0; off >>= 1) s += __shfl_xor(s, off, 64);
    if ((t & 63) == 0) red1[t >> 6] = s;
    __syncthreads();
    float mu = (red1[0] + red1[1] + red1[2] + red1[3]) * (1.0f / D_);
    float q = 0;
#pragma unroll
    for (int i = 0; i < 3; ++i) { float dv = v[i] - mu; q += dv * dv; }
#pragma unroll
    for (int off = 32; off > 0; off >>= 1) q += __shfl_xor(q, off, 64);
    if ((t & 63) == 0) red2[t >> 6] = q;
    __syncthreads();
    float var = (red2[0] + red2[1] + red2[2] + red2[3]) * (1.0f / D_);
    float rs = rsqrtf(var + 1e-12f);
#pragma unroll
    for (int i = 0; i < 3; ++i) {
        int d = t + i * 256;
        out[(size_t)row * D_ + d] = (unsigned short)bf16_rne((v[i] - mu) * rs * g[d] + bb[d]);
    }
}

// ---------------------------------------------------------------------------
// Mean-pool over N then fc
// ---------------------------------------------------------------------------
__global__ __launch_bounds__(256)
void pool_partial_kernel(const unsigned short* __restrict__ X, float* __restrict__ partial) {
    int blk = blockIdx.x;
    int b = blk >> 4, c = blk & 15;
    int t = threadIdx.x;
#pragma unroll
    for (int i = 0; i < 3; ++i) {
        int d = t + i * 256;
        float s = 0.f;
        for (int n = 0; n < 256; ++n)
            s += bfh2f(X[((size_t)(b * N_ + c * 256 + n)) * D_ + d]);
        partial[(size_t)(b * 16 + c) * D_ + d] = s;
    }
}

__global__ __launch_bounds__(256)
void pool_final_kernel(const float* __restrict__ partial, const float* __restrict__ fcw,
                       const float* __restrict__ fcb, float* __restrict__ out) {
    __shared__ float red[4];
    int t = threadIdx.x;
    for (int b = 0; b < B_; ++b) {
        float s = 0.f;
#pragma unroll
        for (int i = 0; i < 3; ++i) {
            int d = t + i * 256;
            float ps = 0.f;
#pragma unroll
            for (int c = 0; c < 16; ++c) ps += partial[(size_t)(b * 16 + c) * D_ + d];
            s += ps * (1.0f / N_) * fcw[d];
        }
#pragma unroll
        for (int off = 32; off > 0; off >>= 1) s += __shfl_xor(s, off, 64);
        __syncthreads();
        if ((t & 63) == 0) red[t >> 6] = s;
        __syncthreads();
        if (t == 0) out[b] = red[0] + red[1] + red[2] + red[3] + fcb[0];
    }
}

// ---------------------------------------------------------------------------
extern "C" void kernel_launch(void* const* d_in, const int* in_sizes, int n_in,
                              void* d_out, int out_size, void* d_ws, size_t ws_size,
                              hipStream_t stream) {
    (void)in_sizes; (void)n_in; (void)out_size; (void)ws_size;
    const float* emb  = (const float*)d_in[0];
    const int*   rblk = (const int*)d_in[1];
    const float* pos  = (const float*)d_in[2];
    const float* tt   = (const float*)d_in[3];
    const float* elg  = (const float*)d_in[4];
    const float* elb  = (const float*)d_in[5];
    const float* Wq   = (const float*)d_in[6];
    const float* bq   = (const float*)d_in[7];
    const float* Wk   = (const float*)d_in[8];
    const float* bk   = (const float*)d_in[9];
    const float* Wv   = (const float*)d_in[10];
    const float* bv   = (const float*)d_in[11];
    const float* Wo   = (const float*)d_in[12];
    const float* bo   = (const float*)d_in[13];
    const float* ln1g = (const float*)d_in[14];
    const float* ln1b = (const float*)d_in[15];
    const float* Wi   = (const float*)d_in[16];
    const float* bi   = (const float*)d_in[17];
    const float* Wd   = (const float*)d_in[18];
    const float* bd   = (const float*)d_in[19];
    const float* ln2g = (const float*)d_in[20];
    const float* ln2b = (const float*)d_in[21];
    const float* fcw  = (const float*)d_in[22];
    const float* fcb  = (const float*)d_in[23];
    float* outp = (float*)d_out;

    const size_t R = (size_t)ROWS_ * D_;          // 6,291,456
    float* base = (float*)d_ws;
    unsigned short* Xh  = (unsigned short*)base;
    unsigned short* Abh = (unsigned short*)(base + R / 2);
    unsigned short* Ob  = (unsigned short*)(base + R);        // bf16 GEMM out (Oproj/FFN2)
    unsigned short* Qh  = (unsigned short*)(base + 2 * R);
    unsigned short* Kh  = (unsigned short*)(base + 2 * R + R / 2);
    unsigned short* VTh = (unsigned short*)(base + 3 * R);
    unsigned short* Ch  = (unsigned short*)(base + 3 * R + R / 2);
    unsigned short* Hh  = (unsigned short*)(base + 2 * R);    // FFN hidden overlays QKVC
    unsigned short* Wt  = (unsigned short*)(base + 4 * R);
    float* Esc = base + 4 * R + 7077888;
    float* Pp  = Esc + 798720;

    const size_t LW = 7077888;
    const int rows = ROWS_;
    dim3 blk(256);

    prep_weights<<<2 * 1728, blk, 0, stream>>>(Wq, Wk, Wv, Wo, Wi, Wd, Wt);

    embed_ln_kernel<<<rows, blk, 0, stream>>>(emb, pos, tt, elg, elb, Xh);

    for (int l = 0; l < LAYERS_; ++l) {
        const float* bq_l = bq + (size_t)l * D_;
        const float* bk_l = bk + (size_t)l * D_;
        const float* bv_l = bv + (size_t)l * D_;
        const float* bo_l = bo + (size_t)l * D_;
        const float* bi_l = bi + (size_t)l * FF_;
        const float* bd_l = bd + (size_t)l * D_;
        const float* l1g = ln1g + (size_t)l * D_;
        const float* l1b = ln1b + (size_t)l * D_;
        const float* l2g = ln2g + (size_t)l * D_;
        const float* l2b = ln2b + (size_t)l * D_;
        const int* rb_l = rblk + (size_t)l * H_ * NB_ * 3;
        unsigned short* QKVt = Wt + l * LW;
        unsigned short* Ot = QKVt + 2304 * 768;
        unsigned short* It = Ot + 768 * 768;
        unsigned short* Dt = It + 3072 * 768;

        gemm_qkv<<<18 * 64, blk, 0, stream>>>(Xh, QKVt, bq_l, bk_l, bv_l, Qh, Kh, VTh);

        attn_mfma<false><<<B_ * H_ * (NB_ - 2), blk, 0, stream>>>(Qh, Kh, VTh, rb_l, Ch, Esc);
        attn_mfma<true><<<B_ * 2 * H_ * 4, blk, 0, stream>>>(Qh, Kh, VTh, rb_l, Ch, Esc);
        edge_combine<<<B_ * 2 * H_, blk, 0, stream>>>(Esc, Ch);

        gemm_bt<1><<<6 * 64, blk, 0, stream>>>(Ch, Ot, bo_l, Ob, D_, D_, 0);
        add_ln_kernel<<<rows, blk, 0, stream>>>(Xh, Ob, l1g, l1b, Abh);

        gemm_bt<1><<<24 * 64, blk, 0, stream>>>(Abh, It, bi_l, Hh, FF_, D_, 1);
        gemm_bt<1><<<6 * 64, blk, 0, stream>>>(Hh, Dt, bd_l, Ob, D_, FF_, 0);

        add_ln_kernel<<<rows, blk, 0, stream>>>(Abh, Ob, l2g, l2b, Xh);
    }

    pool_partial_kernel<<<B_ * 16, blk, 0, stream>>>(Xh, Pp);
    pool_final_kernel<<<1, blk, 0, stream>>>(Pp, fcw, fcb, outp);
}